// Round 1
// baseline (908.923 us; speedup 1.0000x reference)
//
#include <hip/hip_runtime.h>

// Problem constants
#define BATCH 4
#define CCH   256
#define HH    64
#define WW    64
#define HWHW  4096
#define NSP   256
#define NHEAD 8
#define DHEAD 32
#define NSLICE 16
#define SCALE 0.17677669529663689f

// ---------------------------------------------------------------------------
// LayerNorm over channel dim of NCHW
__global__ __launch_bounds__(256)
void ln_kernel(const float* __restrict__ x, const float* __restrict__ w,
               const float* __restrict__ bb, float* __restrict__ xn)
{
    int id = blockIdx.x * 256 + threadIdx.x;   // B*HW = 16384
    int b = id >> 12;
    int n = id & 4095;
    long base = (long)b * CCH * HWHW + n;
    float s = 0.f, ss = 0.f;
    for (int c = 0; c < CCH; ++c) {
        float v = x[base + (long)c * HWHW];
        s += v; ss += v * v;
    }
    float mu  = s * (1.f / CCH);
    float var = ss * (1.f / CCH) - mu * mu;
    float rstd = rsqrtf(var + 1e-6f);
    for (int c = 0; c < CCH; ++c) {
        float v = x[base + (long)c * HWHW];
        xn[base + (long)c * HWHW] = (v - mu) * rstd * w[c] + bb[c];
    }
}

// ---------------------------------------------------------------------------
// Row sums of affinity (B*NSP rows of HW)
__global__ __launch_bounds__(256)
void rowsum_kernel(const float* __restrict__ aff, float* __restrict__ rs)
{
    int row = blockIdx.x;            // b*256+m
    const float* p = aff + (long)row * HWHW;
    int t = threadIdx.x;
    float s = 0.f;
    for (int i = t; i < HWHW; i += 256) s += p[i];
#pragma unroll
    for (int off = 32; off; off >>= 1) s += __shfl_down(s, off, 64);
    __shared__ float red[4];
    if ((t & 63) == 0) red[t >> 6] = s;
    __syncthreads();
    if (t == 0) rs[row] = red[0] + red[1] + red[2] + red[3];
}

// ---------------------------------------------------------------------------
// Tiled fp32 GEMM: C[M,N] = A[M,K] * B   (BT=false: B is K x N row-major;
// BT=true: B is N x K row-major, i.e. dot of rows).  64x64 tile, BK=16,
// 256 threads, 4x4 per thread.  Optional per-column scale (divide by
// colScale[n]+1e-16) for the st projection.
template <bool BT>
__global__ __launch_bounds__(256)
void gemm64(const float* __restrict__ A, const float* __restrict__ Bm,
            float* __restrict__ Cm, int M, int N, int K,
            long aStride, long bStride, long cStride,
            const float* __restrict__ colScaleBase, int sStride)
{
    __shared__ float As[16][68];
    __shared__ float Bs[16][68];
    const int bz = blockIdx.z;
    const float* Ab = A + (long)bz * aStride;
    const float* Bb = Bm + (long)bz * bStride;
    float* Cb = Cm + (long)bz * cStride;
    const int mt = blockIdx.y * 64;
    const int nt = blockIdx.x * 64;
    const int t = threadIdx.x;
    const int tx = t & 15, ty = t >> 4;
    float acc[4][4] = {};
    for (int k0 = 0; k0 < K; k0 += 16) {
#pragma unroll
        for (int i = 0; i < 4; ++i) {           // A tile: 64 m x 16 k
            int idx = t + i * 256;
            int mm = idx >> 4, kk = idx & 15;
            As[kk][mm] = Ab[(long)(mt + mm) * K + k0 + kk];
        }
        if (!BT) {
#pragma unroll
            for (int i = 0; i < 4; ++i) {       // B tile: 16 k x 64 n
                int idx = t + i * 256;
                int kk = idx >> 6, nn = idx & 63;
                Bs[kk][nn] = Bb[(long)(k0 + kk) * N + nt + nn];
            }
        } else {
#pragma unroll
            for (int i = 0; i < 4; ++i) {       // B tile: 64 n x 16 k
                int idx = t + i * 256;
                int nn = idx >> 4, kk = idx & 15;
                Bs[kk][nn] = Bb[(long)(nt + nn) * K + k0 + kk];
            }
        }
        __syncthreads();
#pragma unroll
        for (int kk = 0; kk < 16; ++kk) {
            float4 a4 = *(const float4*)&As[kk][ty * 4];
            float4 b4 = *(const float4*)&Bs[kk][tx * 4];
            float av[4] = {a4.x, a4.y, a4.z, a4.w};
            float bv[4] = {b4.x, b4.y, b4.z, b4.w};
#pragma unroll
            for (int i = 0; i < 4; ++i)
#pragma unroll
                for (int j = 0; j < 4; ++j) acc[i][j] += av[i] * bv[j];
        }
        __syncthreads();
    }
#pragma unroll
    for (int i = 0; i < 4; ++i) {
        int m = mt + ty * 4 + i;
#pragma unroll
        for (int j = 0; j < 4; ++j) {
            int n = nt + tx * 4 + j;
            float v = acc[i][j];
            if (colScaleBase) {
                float r = colScaleBase[(long)sStride * bz + n];
                v = v / (r + 1e-16f);
            }
            Cb[(long)m * N + n] = v;
        }
    }
}

// ---------------------------------------------------------------------------
// Stage-1 attention (queries = st columns, keys = k, values = v, softmax over
// the 4096 key axis).  Key-split into NSLICE slices; exact partials out.
__global__ __launch_bounds__(256)
void stage1_kernel(const float* __restrict__ k_g, const float* __restrict__ v_g,
                   const float* __restrict__ st_g,
                   float* __restrict__ pmax, float* __restrict__ psum,
                   float* __restrict__ pacc)
{
    __shared__ float klds[32][256];
    __shared__ float vlds[32][256];
    int slice = blockIdx.x;      // 0..15
    int h = blockIdx.y;          // 0..7
    int b = blockIdx.z;          // 0..3
    int t = threadIdx.x;         // query m
    int bh = b * NHEAD + h;
    const long kvbase = ((long)(b * CCH + h * DHEAD)) * HWHW + slice * 256;
#pragma unroll 4
    for (int d = 0; d < 32; ++d) {
        klds[d][t] = k_g[kvbase + (long)d * HWHW + t];
        vlds[d][t] = v_g[kvbase + (long)d * HWHW + t];
    }
    float stq[32];
    const long stb = (long)(b * CCH + h * DHEAD) * NSP + t;
#pragma unroll
    for (int d = 0; d < 32; ++d) stq[d] = st_g[stb + d * NSP];
    __syncthreads();

    // pass 1: max of logits
    float lmax = -1e30f;
    for (int j = 0; j < 64; ++j) {
        float l0 = 0.f, l1 = 0.f, l2 = 0.f, l3 = 0.f;
#pragma unroll
        for (int d = 0; d < 32; ++d) {
            float4 k4 = *(const float4*)&klds[d][j * 4];
            float s = stq[d];
            l0 += k4.x * s; l1 += k4.y * s; l2 += k4.z * s; l3 += k4.w * s;
        }
        lmax = fmaxf(lmax, fmaxf(fmaxf(l0, l1), fmaxf(l2, l3)));
    }
    lmax *= SCALE;
    // pass 2: exp-sum and value accumulation
    float lsum = 0.f;
    float acc[32] = {};
    for (int j = 0; j < 64; ++j) {
        float l0 = 0.f, l1 = 0.f, l2 = 0.f, l3 = 0.f;
#pragma unroll
        for (int d = 0; d < 32; ++d) {
            float4 k4 = *(const float4*)&klds[d][j * 4];
            float s = stq[d];
            l0 += k4.x * s; l1 += k4.y * s; l2 += k4.z * s; l3 += k4.w * s;
        }
        float e0 = __expf(l0 * SCALE - lmax);
        float e1 = __expf(l1 * SCALE - lmax);
        float e2 = __expf(l2 * SCALE - lmax);
        float e3 = __expf(l3 * SCALE - lmax);
        lsum += (e0 + e1) + (e2 + e3);
#pragma unroll
        for (int d = 0; d < 32; ++d) {
            float4 v4 = *(const float4*)&vlds[d][j * 4];
            acc[d] += e0 * v4.x + e1 * v4.y + e2 * v4.z + e3 * v4.w;
        }
    }
    int pbase = (bh * NSLICE + slice) * 256 + t;
    pmax[pbase] = lmax;
    psum[pbase] = lsum;
    long accbase = ((long)(bh * NSLICE + slice) * 32) * 256 + t;
#pragma unroll
    for (int d = 0; d < 32; ++d) pacc[accbase + d * 256] = acc[d];
}

// Merge stage-1 partials -> s_out[b][o][m]
__global__ __launch_bounds__(256)
void merge1_kernel(const float* __restrict__ pmax, const float* __restrict__ psum,
                   const float* __restrict__ pacc, float* __restrict__ sout)
{
    int t = blockIdx.x * 256 + threadIdx.x;   // 262144
    int m = t & 255;
    int d = (t >> 8) & 31;
    int bh = t >> 13;
    float gmax = -1e30f;
    for (int s = 0; s < NSLICE; ++s)
        gmax = fmaxf(gmax, pmax[(bh * NSLICE + s) * 256 + m]);
    float lsum = 0.f, acc = 0.f;
    for (int s = 0; s < NSLICE; ++s) {
        float w = __expf(pmax[(bh * NSLICE + s) * 256 + m] - gmax);
        lsum += w * psum[(bh * NSLICE + s) * 256 + m];
        acc  += w * pacc[((long)(bh * NSLICE + s) * 32 + d) * 256 + m];
    }
    sout[((long)bh * 32 + d) * 256 + m] = acc / lsum;
}

// ---------------------------------------------------------------------------
// Stage-2 attention (queries = q pixels, keys = st, values = s_out, softmax
// over the 256 superpixel axis).  Writes x_out to d_out.
__global__ __launch_bounds__(256)
void stage2_kernel(const float* __restrict__ q_g, const float* __restrict__ st_g,
                   const float* __restrict__ so_g, float* __restrict__ out)
{
    __shared__ float st_s[32][256];
    __shared__ float so_s[32][256];
    int nt = blockIdx.x;   // 0..15
    int h = blockIdx.y;
    int b = blockIdx.z;
    int t = threadIdx.x;
    long base = (long)(b * CCH + h * DHEAD) * NSP;
#pragma unroll 4
    for (int d = 0; d < 32; ++d) {
        st_s[d][t] = st_g[base + d * NSP + t];
        so_s[d][t] = so_g[base + d * NSP + t];
    }
    __syncthreads();
    int n = nt * 256 + t;
    float qv[32];
    long qbase = (long)(b * CCH + h * DHEAD) * HWHW + n;
#pragma unroll
    for (int d = 0; d < 32; ++d) qv[d] = q_g[qbase + (long)d * HWHW];

    float lmax = -1e30f;
    for (int j = 0; j < 64; ++j) {
        float l0 = 0.f, l1 = 0.f, l2 = 0.f, l3 = 0.f;
#pragma unroll
        for (int d = 0; d < 32; ++d) {
            float4 k4 = *(const float4*)&st_s[d][j * 4];
            float s = qv[d];
            l0 += k4.x * s; l1 += k4.y * s; l2 += k4.z * s; l3 += k4.w * s;
        }
        lmax = fmaxf(lmax, fmaxf(fmaxf(l0, l1), fmaxf(l2, l3)));
    }
    lmax *= SCALE;
    float lsum = 0.f;
    float acc[32] = {};
    for (int j = 0; j < 64; ++j) {
        float l0 = 0.f, l1 = 0.f, l2 = 0.f, l3 = 0.f;
#pragma unroll
        for (int d = 0; d < 32; ++d) {
            float4 k4 = *(const float4*)&st_s[d][j * 4];
            float s = qv[d];
            l0 += k4.x * s; l1 += k4.y * s; l2 += k4.z * s; l3 += k4.w * s;
        }
        float e0 = __expf(l0 * SCALE - lmax);
        float e1 = __expf(l1 * SCALE - lmax);
        float e2 = __expf(l2 * SCALE - lmax);
        float e3 = __expf(l3 * SCALE - lmax);
        lsum += (e0 + e1) + (e2 + e3);
#pragma unroll
        for (int d = 0; d < 32; ++d) {
            float4 v4 = *(const float4*)&so_s[d][j * 4];
            acc[d] += e0 * v4.x + e1 * v4.y + e2 * v4.z + e3 * v4.w;
        }
    }
    float inv = 1.f / lsum;
    long obase = (long)(b * CCH + h * DHEAD) * HWHW + n;
#pragma unroll
    for (int d = 0; d < 32; ++d) out[obase + (long)d * HWHW] = acc[d] * inv;
}

// ---------------------------------------------------------------------------
// Depthwise 3x3 conv on v(x) + bias
__global__ __launch_bounds__(256)
void lepe_conv_kernel(const float* __restrict__ vx, const float* __restrict__ lw,
                      const float* __restrict__ lb, float* __restrict__ outc)
{
    int idx = blockIdx.x * 256 + threadIdx.x;   // 4194304
    int n = idx & 4095;
    int c = (idx >> 12) & 255;
    int b = idx >> 20;
    int hh = n >> 6, ww = n & 63;
    const float* src = vx + ((long)(b * CCH + c) << 12);
    float acc = lb[c];
#pragma unroll
    for (int kh = 0; kh < 3; ++kh) {
        int h2 = hh + kh - 1;
        if ((unsigned)h2 < 64u) {
#pragma unroll
            for (int kw = 0; kw < 3; ++kw) {
                int w2 = ww + kw - 1;
                if ((unsigned)w2 < 64u)
                    acc += src[h2 * 64 + w2] * lw[c * 9 + kh * 3 + kw];
            }
        }
    }
    outc[idx] = acc;
}

// Scrambled lepe add: out[b,c,n] += conv[b, n&255, c*16 + (n>>8)]
__global__ __launch_bounds__(256)
void lepe_add_kernel(const float* __restrict__ convb, float* __restrict__ out)
{
    int idx = blockIdx.x * 256 + threadIdx.x;
    int n = idx & 4095;
    int c = (idx >> 12) & 255;
    int b = idx >> 20;
    int cs = n & 255;
    int hws = (c << 4) | (n >> 8);
    out[idx] += convb[(((long)(b * CCH + cs)) << 12) + hws];
}

// ---------------------------------------------------------------------------
extern "C" void kernel_launch(void* const* d_in, const int* in_sizes, int n_in,
                              void* d_out, int out_size, void* d_ws, size_t ws_size,
                              hipStream_t stream)
{
    const float* x    = (const float*)d_in[0];
    const float* aff  = (const float*)d_in[1];
    const float* nw   = (const float*)d_in[2];
    const float* nb   = (const float*)d_in[3];
    const float* Wq   = (const float*)d_in[4];
    const float* Wk   = (const float*)d_in[5];
    const float* Wv   = (const float*)d_in[6];
    const float* Wsp  = (const float*)d_in[7];
    const float* lw   = (const float*)d_in[8];
    const float* lb   = (const float*)d_in[9];
    float* out = (float*)d_out;

    float* ws = (float*)d_ws;
    const long PLANE = (long)CCH * HWHW;           // 1,048,576 per batch
    float* xn     = ws;                            // 4 * PLANE (also conv buffer later)
    float* q      = ws + 4 * PLANE;
    float* k      = ws + 8 * PLANE;
    float* v      = ws + 12 * PLANE;
    float* stoken = ws + 16 * PLANE;               // B*256*256
    float* st     = stoken + (long)BATCH * NSP * CCH;
    float* sout   = st + (long)BATCH * CCH * NSP;
    float* rs     = sout + (long)BATCH * CCH * NSP;
    float* pmax   = rs + BATCH * NSP;              // B*NH*NSLICE*256
    float* psum   = pmax + (long)BATCH * NHEAD * NSLICE * 256;
    float* pacc   = psum + (long)BATCH * NHEAD * NSLICE * 256;  // B*NH*NSLICE*32*256
    float* convb  = xn;                            // alias: xn dead after GEMMs

    // 1. LayerNorm
    ln_kernel<<<64, 256, 0, stream>>>(x, nw, nb, xn);
    // 2. affinity row sums
    rowsum_kernel<<<BATCH * NSP, 256, 0, stream>>>(aff, rs);
    // 3. stoken[m][c] = sum_n aff[m][n] * xn[c][n]   (NT, K=4096)
    gemm64<true><<<dim3(4, 4, BATCH), 256, 0, stream>>>(
        aff, xn, stoken, 256, 256, 4096, PLANE, PLANE, (long)NSP * CCH, nullptr, 0);
    // 4. st[o][m] = sum_c Wsp[o][c] * stoken[m][c] / (rowsum[m]+eps)   (NT, K=256)
    gemm64<true><<<dim3(4, 4, BATCH), 256, 0, stream>>>(
        Wsp, stoken, st, 256, 256, 256, 0, (long)NSP * CCH, (long)CCH * NSP, rs, NSP);
    // 5-7. q/k/v projections: out[o][n] = sum_c W[o][c] * xn[c][n]   (NN, K=256)
    gemm64<false><<<dim3(64, 4, BATCH), 256, 0, stream>>>(
        Wq, xn, q, 256, 4096, 256, 0, PLANE, PLANE, nullptr, 0);
    gemm64<false><<<dim3(64, 4, BATCH), 256, 0, stream>>>(
        Wk, xn, k, 256, 4096, 256, 0, PLANE, PLANE, nullptr, 0);
    gemm64<false><<<dim3(64, 4, BATCH), 256, 0, stream>>>(
        Wv, xn, v, 256, 4096, 256, 0, PLANE, PLANE, nullptr, 0);
    // 8. stage-1 attention partials
    stage1_kernel<<<dim3(NSLICE, NHEAD, BATCH), 256, 0, stream>>>(
        k, v, st, pmax, psum, pacc);
    // 9. merge -> s_out
    merge1_kernel<<<1024, 256, 0, stream>>>(pmax, psum, pacc, sout);
    // 10. depthwise conv (into xn region, now dead)
    lepe_conv_kernel<<<16384, 256, 0, stream>>>(v, lw, lb, convb);
    // 11. stage-2 attention -> d_out
    stage2_kernel<<<dim3(16, NHEAD, BATCH), 256, 0, stream>>>(q, st, sout, out);
    // 12. scrambled lepe add
    lepe_add_kernel<<<16384, 256, 0, stream>>>(convb, out);
}

// Round 3
// 446.682 us; speedup vs baseline: 2.0348x; 2.0348x over previous
//
#include <hip/hip_runtime.h>
#include <hip/hip_bf16.h>

#define BATCH 4
#define CCH   256
#define HWHW  4096
#define NSP   256
#define NHEAD 8
#define SCALE 0.17677669529663689f
#define PLANE 1048576L   // 256*4096 elements per batch

typedef short bf16x8 __attribute__((ext_vector_type(8)));
typedef float f32x4  __attribute__((ext_vector_type(4)));

// ---------------------------------------------------------------------------
// LayerNorm over channel dim, output bf16 in [b][c][n] layout
__global__ __launch_bounds__(256)
void ln_kernel(const float* __restrict__ x, const float* __restrict__ w,
               const float* __restrict__ bb, __hip_bfloat16* __restrict__ xn)
{
    int id = blockIdx.x * 256 + threadIdx.x;   // B*HW = 16384
    int b = id >> 12;
    int n = id & 4095;
    long base = (long)b * CCH * HWHW + n;
    float s = 0.f, ss = 0.f;
    for (int c = 0; c < CCH; ++c) {
        float v = x[base + (long)c * HWHW];
        s += v; ss += v * v;
    }
    float mu  = s * (1.f / CCH);
    float var = ss * (1.f / CCH) - mu * mu;
    float rstd = rsqrtf(var + 1e-6f);
    for (int c = 0; c < CCH; ++c) {
        float v = x[base + (long)c * HWHW];
        xn[base + (long)c * HWHW] = __float2bfloat16((v - mu) * rstd * w[c] + bb[c]);
    }
}

// bf16 [c][n] -> [n][c] transpose (per batch)
__global__ __launch_bounds__(256)
void transpose_bf16_kernel(const __hip_bfloat16* __restrict__ in,
                           __hip_bfloat16* __restrict__ out)
{
    __shared__ __hip_bfloat16 tile[64][65];
    int n0 = blockIdx.x * 64, c0 = blockIdx.y * 64, b = blockIdx.z;
    int t = threadIdx.x;
#pragma unroll
    for (int i = 0; i < 16; ++i) {
        int idx = t + i * 256;
        int ci = idx >> 6, ni = idx & 63;
        tile[ci][ni] = in[((long)(b * CCH + c0 + ci)) * HWHW + n0 + ni];
    }
    __syncthreads();
#pragma unroll
    for (int i = 0; i < 16; ++i) {
        int idx = t + i * 256;
        int ni = idx >> 6, ci = idx & 63;
        out[((long)b * HWHW + n0 + ni) * CCH + c0 + ci] = tile[ci][ni];
    }
}

// generic fp32 -> bf16 cast
__global__ __launch_bounds__(256)
void cast_bf16_kernel(const float* __restrict__ in, __hip_bfloat16* __restrict__ out, int n)
{
    int i = blockIdx.x * 256 + threadIdx.x;
    if (i < n) out[i] = __float2bfloat16(in[i]);
}

// Deterministic split-K reduction: stoken_bf[b][m][c] = bf16(sum_ch part[b*4+ch])
__global__ __launch_bounds__(256)
void reduce4_cast_kernel(const float* __restrict__ part, __hip_bfloat16* __restrict__ out)
{
    int i = blockIdx.x * 256 + threadIdx.x;   // 262144
    int b = i >> 16, idx = i & 65535;
    long base = (long)b * 4 * 65536 + idx;
    float s = part[base] + part[base + 65536] + part[base + 131072] + part[base + 196608];
    out[i] = __float2bfloat16(s);
}

// ---------------------------------------------------------------------------
// Row sums of affinity (B*NSP rows of HW)
__global__ __launch_bounds__(256)
void rowsum_kernel(const float* __restrict__ aff, float* __restrict__ rs)
{
    int row = blockIdx.x;
    const float* p = aff + (long)row * HWHW;
    int t = threadIdx.x;
    float s = 0.f;
    for (int i = t; i < HWHW; i += 256) s += p[i];
#pragma unroll
    for (int off = 32; off; off >>= 1) s += __shfl_down(s, off, 64);
    __shared__ float red[4];
    if ((t & 63) == 0) red[t >> 6] = s;
    __syncthreads();
    if (t == 0) rs[row] = red[0] + red[1] + red[2] + red[3];
}

// ---------------------------------------------------------------------------
// bf16 MFMA NT GEMM: C[m][n] = sum_k A[m][k]*B[n][k]
// A rows m (row stride K), B rows n (row stride K), C row-major ld=N.
// grid: x=N/64, y=M/64, z = nbatch << kShift.  A/B batch index = z>>kShift,
// K-chunk = z & mask.  C chunk index = z (partials disjoint; deterministic).
template <bool COLSCALE>
__global__ __launch_bounds__(256)
void mfma_gemm_nt(const __hip_bfloat16* __restrict__ A,
                  const __hip_bfloat16* __restrict__ B,
                  float* __restrict__ C, int N, int K, int kChunk, int kShift,
                  long aStrideZ, long bStrideZ, long cStrideZ,
                  const float* __restrict__ colScale, long sStrideZ)
{
    __shared__ __hip_bfloat16 Asm[4 * 64 * 8];   // [mtile][lane][8]
    __shared__ __hip_bfloat16 Bsm[4 * 64 * 8];
    int z = blockIdx.z;
    int b = z >> kShift;
    int ch = z & ((1 << kShift) - 1);
    const __hip_bfloat16* Ab = A + b * aStrideZ + (long)ch * kChunk;
    const __hip_bfloat16* Bb = B + b * bStrideZ + (long)ch * kChunk;
    float* Cb = C + (long)z * cStrideZ;
    int t = threadIdx.x;
    int lane = t & 63, w = t >> 6;
    int l15 = lane & 15, quad = lane >> 4;
    int Mt = blockIdx.y * 64, Nt = blockIdx.x * 64;

    const __hip_bfloat16* aSrc = Ab + (long)(Mt + w * 16 + l15) * K + quad * 8;
    const __hip_bfloat16* bSrc = Bb + (long)(Nt + w * 16 + l15) * K + quad * 8;
    __hip_bfloat16* aDst = &Asm[t * 8];
    __hip_bfloat16* bDst = &Bsm[t * 8];

    f32x4 acc00 = {0.f,0.f,0.f,0.f}, acc01 = acc00, acc10 = acc00, acc11 = acc00;
    int wm = (w & 1) * 2, wn = (w >> 1) * 2;

    for (int k0 = 0; k0 < kChunk; k0 += 32) {
        *(int4*)aDst = *(const int4*)aSrc;
        *(int4*)bDst = *(const int4*)bSrc;
        aSrc += 32; bSrc += 32;
        __syncthreads();
        bf16x8 a0 = ((const bf16x8*)Asm)[wm * 64 + lane];
        bf16x8 a1 = ((const bf16x8*)Asm)[(wm + 1) * 64 + lane];
        bf16x8 b0 = ((const bf16x8*)Bsm)[wn * 64 + lane];
        bf16x8 b1 = ((const bf16x8*)Bsm)[(wn + 1) * 64 + lane];
        acc00 = __builtin_amdgcn_mfma_f32_16x16x32_bf16(a0, b0, acc00, 0, 0, 0);
        acc01 = __builtin_amdgcn_mfma_f32_16x16x32_bf16(a0, b1, acc01, 0, 0, 0);
        acc10 = __builtin_amdgcn_mfma_f32_16x16x32_bf16(a1, b0, acc10, 0, 0, 0);
        acc11 = __builtin_amdgcn_mfma_f32_16x16x32_bf16(a1, b1, acc11, 0, 0, 0);
        __syncthreads();
    }
    // epilogue: D row = quad*4+reg (m), col = lane&15 (n)
    f32x4 accs[2][2] = {{acc00, acc01}, {acc10, acc11}};
#pragma unroll
    for (int i = 0; i < 2; ++i)
#pragma unroll
        for (int j = 0; j < 2; ++j)
#pragma unroll
            for (int r = 0; r < 4; ++r) {
                int m = Mt + (wm + i) * 16 + quad * 4 + r;
                int n = Nt + (wn + j) * 16 + l15;
                float val = accs[i][j][r];
                if (COLSCALE) val /= (colScale[(long)b * sStrideZ + n] + 1e-16f);
                Cb[(long)m * N + n] = val;
            }
}

// ---------------------------------------------------------------------------
// Stage-1 attention partials: queries = st columns (256), keys/values = k,v
// slice of 256 pixels.  2 queries per thread, key-half split, single-pass
// softmax with max=0 (logits are tiny; mathematically identical).
__global__ __launch_bounds__(256)
void stage1_kernel(const float* __restrict__ k_g, const float* __restrict__ v_g,
                   const float* __restrict__ st_g,
                   float* __restrict__ psum, float* __restrict__ pacc)
{
    __shared__ float smem[2][32][256];   // k, v
    int slice = blockIdx.x, h = blockIdx.y, b = blockIdx.z;
    int t = threadIdx.x;
    int tq = t & 127, kh = t >> 7;
    int bh = b * NHEAD + h;
    long kvbase = ((long)(b * CCH + h * 32)) * HWHW + slice * 256;
#pragma unroll 4
    for (int d = 0; d < 32; ++d) {
        smem[0][d][t] = k_g[kvbase + (long)d * HWHW + t];
        smem[1][d][t] = v_g[kvbase + (long)d * HWHW + t];
    }
    float s0[32], s1[32];
    long stb = (long)(b * CCH + h * 32) * NSP;
#pragma unroll
    for (int d = 0; d < 32; ++d) {
        s0[d] = st_g[stb + d * NSP + tq];
        s1[d] = st_g[stb + d * NSP + tq + 128];
    }
    __syncthreads();

    float acc0[32] = {}, acc1[32] = {};
    float sum0 = 0.f, sum1 = 0.f;
    int kb = kh * 128;
    for (int j = 0; j < 32; ++j) {
        float l00 = 0, l01 = 0, l02 = 0, l03 = 0;
        float l10 = 0, l11 = 0, l12 = 0, l13 = 0;
#pragma unroll
        for (int d = 0; d < 32; ++d) {
            float4 k4 = *(const float4*)&smem[0][d][kb + j * 4];
            float a = s0[d], c = s1[d];
            l00 += k4.x * a; l01 += k4.y * a; l02 += k4.z * a; l03 += k4.w * a;
            l10 += k4.x * c; l11 += k4.y * c; l12 += k4.z * c; l13 += k4.w * c;
        }
        float e00 = __expf(l00 * SCALE), e01 = __expf(l01 * SCALE);
        float e02 = __expf(l02 * SCALE), e03 = __expf(l03 * SCALE);
        float e10 = __expf(l10 * SCALE), e11 = __expf(l11 * SCALE);
        float e12 = __expf(l12 * SCALE), e13 = __expf(l13 * SCALE);
        sum0 += (e00 + e01) + (e02 + e03);
        sum1 += (e10 + e11) + (e12 + e13);
#pragma unroll
        for (int d = 0; d < 32; ++d) {
            float4 v4 = *(const float4*)&smem[1][d][kb + j * 4];
            acc0[d] += e00 * v4.x + e01 * v4.y + e02 * v4.z + e03 * v4.w;
            acc1[d] += e10 * v4.x + e11 * v4.y + e12 * v4.z + e13 * v4.w;
        }
    }
    __syncthreads();
    // merge key-halves: buffer [dslot][q][132]
    float* mb = &smem[0][0][0];
    if (kh == 1) {
#pragma unroll
        for (int d = 0; d < 32; ++d) {
            mb[(d * 2 + 0) * 132 + tq] = acc0[d];
            mb[(d * 2 + 1) * 132 + tq] = acc1[d];
        }
        mb[64 * 132 + tq] = sum0;
        mb[65 * 132 + tq] = sum1;
    }
    __syncthreads();
    if (kh == 0) {
#pragma unroll
        for (int d = 0; d < 32; ++d) {
            acc0[d] += mb[(d * 2 + 0) * 132 + tq];
            acc1[d] += mb[(d * 2 + 1) * 132 + tq];
        }
        sum0 += mb[64 * 132 + tq];
        sum1 += mb[65 * 132 + tq];
        int pb = (bh * 16 + slice) * 256;
        psum[pb + tq]       = sum0;
        psum[pb + tq + 128] = sum1;
        long ab = ((long)(bh * 16 + slice) * 32) * 256;
#pragma unroll
        for (int d = 0; d < 32; ++d) {
            pacc[ab + d * 256 + tq]       = acc0[d];
            pacc[ab + d * 256 + tq + 128] = acc1[d];
        }
    }
}

// Merge stage-1 partials -> s_out[bh][d][m]
__global__ __launch_bounds__(256)
void merge1_kernel(const float* __restrict__ psum, const float* __restrict__ pacc,
                   float* __restrict__ sout)
{
    int t = blockIdx.x * 256 + threadIdx.x;   // 262144
    int m = t & 255;
    int d = (t >> 8) & 31;
    int bh = t >> 13;
    float lsum = 0.f, acc = 0.f;
    for (int s = 0; s < 16; ++s) {
        lsum += psum[(bh * 16 + s) * 256 + m];
        acc  += pacc[((long)(bh * 16 + s) * 32 + d) * 256 + m];
    }
    sout[((long)bh * 32 + d) * 256 + m] = acc / lsum;
}

// ---------------------------------------------------------------------------
// Stage-2 attention: queries = q pixels, keys = st, values = s_out.
// 2 queries/thread, key-half split, single pass (max=0).
__global__ __launch_bounds__(256)
void stage2_kernel(const float* __restrict__ q_g, const float* __restrict__ st_g,
                   const float* __restrict__ so_g, float* __restrict__ out)
{
    __shared__ float smem[2][32][256];   // st, sout
    int nt = blockIdx.x, h = blockIdx.y, b = blockIdx.z;
    int t = threadIdx.x;
    int tq = t & 127, kh = t >> 7;
    long stb = (long)(b * CCH + h * 32) * NSP;
#pragma unroll 4
    for (int d = 0; d < 32; ++d) {
        smem[0][d][t] = st_g[stb + d * NSP + t];
        smem[1][d][t] = so_g[stb + d * NSP + t];
    }
    int n0 = nt * 256 + tq;
    float q0[32], q1[32];
    long qbase = (long)(b * CCH + h * 32) * HWHW;
#pragma unroll
    for (int d = 0; d < 32; ++d) {
        q0[d] = q_g[qbase + (long)d * HWHW + n0];
        q1[d] = q_g[qbase + (long)d * HWHW + n0 + 128];
    }
    __syncthreads();

    float acc0[32] = {}, acc1[32] = {};
    float sum0 = 0.f, sum1 = 0.f;
    int kb = kh * 128;
    for (int j = 0; j < 32; ++j) {
        float l00 = 0, l01 = 0, l02 = 0, l03 = 0;
        float l10 = 0, l11 = 0, l12 = 0, l13 = 0;
#pragma unroll
        for (int d = 0; d < 32; ++d) {
            float4 k4 = *(const float4*)&smem[0][d][kb + j * 4];
            float a = q0[d], c = q1[d];
            l00 += k4.x * a; l01 += k4.y * a; l02 += k4.z * a; l03 += k4.w * a;
            l10 += k4.x * c; l11 += k4.y * c; l12 += k4.z * c; l13 += k4.w * c;
        }
        float e00 = __expf(l00 * SCALE), e01 = __expf(l01 * SCALE);
        float e02 = __expf(l02 * SCALE), e03 = __expf(l03 * SCALE);
        float e10 = __expf(l10 * SCALE), e11 = __expf(l11 * SCALE);
        float e12 = __expf(l12 * SCALE), e13 = __expf(l13 * SCALE);
        sum0 += (e00 + e01) + (e02 + e03);
        sum1 += (e10 + e11) + (e12 + e13);
#pragma unroll
        for (int d = 0; d < 32; ++d) {
            float4 v4 = *(const float4*)&smem[1][d][kb + j * 4];
            acc0[d] += e00 * v4.x + e01 * v4.y + e02 * v4.z + e03 * v4.w;
            acc1[d] += e10 * v4.x + e11 * v4.y + e12 * v4.z + e13 * v4.w;
        }
    }
    __syncthreads();
    float* mb = &smem[0][0][0];
    if (kh == 1) {
#pragma unroll
        for (int d = 0; d < 32; ++d) {
            mb[(d * 2 + 0) * 132 + tq] = acc0[d];
            mb[(d * 2 + 1) * 132 + tq] = acc1[d];
        }
        mb[64 * 132 + tq] = sum0;
        mb[65 * 132 + tq] = sum1;
    }
    __syncthreads();
    if (kh == 0) {
#pragma unroll
        for (int d = 0; d < 32; ++d) {
            acc0[d] += mb[(d * 2 + 0) * 132 + tq];
            acc1[d] += mb[(d * 2 + 1) * 132 + tq];
        }
        sum0 += mb[64 * 132 + tq];
        sum1 += mb[65 * 132 + tq];
        float i0 = 1.f / sum0, i1 = 1.f / sum1;
        long ob = (long)(b * CCH + h * 32) * HWHW + nt * 256 + tq;
#pragma unroll
        for (int d = 0; d < 32; ++d) {
            out[ob + (long)d * HWHW]       = acc0[d] * i0;
            out[ob + (long)d * HWHW + 128] = acc1[d] * i1;
        }
    }
}

// ---------------------------------------------------------------------------
// Depthwise 3x3 conv on v(x) + bias
__global__ __launch_bounds__(256)
void lepe_conv_kernel(const float* __restrict__ vx, const float* __restrict__ lw,
                      const float* __restrict__ lb, float* __restrict__ outc)
{
    int idx = blockIdx.x * 256 + threadIdx.x;   // 4194304
    int n = idx & 4095;
    int c = (idx >> 12) & 255;
    int b = idx >> 20;
    int hh = n >> 6, ww = n & 63;
    const float* src = vx + ((long)(b * CCH + c) << 12);
    float acc = lb[c];
#pragma unroll
    for (int kh = 0; kh < 3; ++kh) {
        int h2 = hh + kh - 1;
        if ((unsigned)h2 < 64u) {
#pragma unroll
            for (int kw = 0; kw < 3; ++kw) {
                int w2 = ww + kw - 1;
                if ((unsigned)w2 < 64u)
                    acc += src[h2 * 64 + w2] * lw[c * 9 + kh * 3 + kw];
            }
        }
    }
    outc[idx] = acc;
}

// Scrambled lepe add, LDS-transposed for coalescing:
// conv[b][c'][n'] adds to out[b][n'>>4][(n'&15)*256 + c']
__global__ __launch_bounds__(256)
void lepe_tadd_kernel(const float* __restrict__ convb, float* __restrict__ out)
{
    __shared__ float tile[256][33];
    int n0 = blockIdx.x * 256;   // n' tile
    int c0 = blockIdx.y * 32;    // c' tile
    int b  = blockIdx.z;
    int t = threadIdx.x;
#pragma unroll
    for (int i = 0; i < 32; ++i) {
        int idx = t + i * 256;
        int ci = idx >> 8, nl = idx & 255;
        tile[nl][ci] = convb[((long)(b * CCH + c0 + ci) << 12) + n0 + nl];
    }
    __syncthreads();
#pragma unroll
    for (int i = 0; i < 32; ++i) {
        int idx = t + i * 256;
        int nl = idx >> 5, ci = idx & 31;
        int c2 = (n0 + nl) >> 4;
        int n2 = (nl & 15) * 256 + c0 + ci;
        out[((long)(b * CCH + c2) << 12) + n2] += tile[nl][ci];
    }
}

// ---------------------------------------------------------------------------
extern "C" void kernel_launch(void* const* d_in, const int* in_sizes, int n_in,
                              void* d_out, int out_size, void* d_ws, size_t ws_size,
                              hipStream_t stream)
{
    const float* x    = (const float*)d_in[0];
    const float* aff  = (const float*)d_in[1];
    const float* nw   = (const float*)d_in[2];
    const float* nb   = (const float*)d_in[3];
    const float* Wq   = (const float*)d_in[4];
    const float* Wk   = (const float*)d_in[5];
    const float* Wv   = (const float*)d_in[6];
    const float* Wsp  = (const float*)d_in[7];
    const float* lw   = (const float*)d_in[8];
    const float* lb   = (const float*)d_in[9];
    float* out = (float*)d_out;

    float* ws = (float*)d_ws;
    const long P = PLANE;
    float* q      = ws;                 // 4P floats
    float* k      = ws + 4 * P;         // 4P
    float* v      = ws + 8 * P;         // 4P
    __hip_bfloat16* xn_cn = (__hip_bfloat16*)(ws + 12 * P);  // 4P bf16 = 2P floats
    __hip_bfloat16* xn_nc = (__hip_bfloat16*)(ws + 14 * P);  // 4P bf16 = 2P floats
    float* pacc   = ws + 12 * P;        // alias over xn (dead after GEMMs), 4P floats
    __hip_bfloat16* aff_bf = (__hip_bfloat16*)(ws + 16 * P); // 4P bf16 = 2P floats
    __hip_bfloat16* Wq_bf  = (__hip_bfloat16*)(ws + 18 * P);
    __hip_bfloat16* Wk_bf  = Wq_bf + 65536;
    __hip_bfloat16* Wv_bf  = Wk_bf + 65536;
    __hip_bfloat16* Wsp_bf = Wv_bf + 65536;
    float* stoken_part = ws + 18 * P + 131072;        // 16 * 65536 = 1,048,576 floats
    __hip_bfloat16* stoken_bf = (__hip_bfloat16*)(ws + 18 * P + 1179648); // 262144 bf16
    float* st     = ws + 18 * P + 1310720;            // 262144
    float* sout   = ws + 18 * P + 1572864;            // 262144
    float* rs     = ws + 18 * P + 1835008;            // 1024
    float* psum   = rs + 1024;                        // 131072
    float* convb  = k;                  // alias: k dead after stage1

    // 1. LayerNorm -> xn_cn (bf16)
    ln_kernel<<<64, 256, 0, stream>>>(x, nw, nb, xn_cn);
    // 2. transpose -> xn_nc (bf16)
    transpose_bf16_kernel<<<dim3(64, 4, BATCH), 256, 0, stream>>>(xn_cn, xn_nc);
    // 3. casts
    cast_bf16_kernel<<<16384, 256, 0, stream>>>(aff, aff_bf, BATCH * NSP * HWHW);
    cast_bf16_kernel<<<256, 256, 0, stream>>>(Wq, Wq_bf, 65536);
    cast_bf16_kernel<<<256, 256, 0, stream>>>(Wk, Wk_bf, 65536);
    cast_bf16_kernel<<<256, 256, 0, stream>>>(Wv, Wv_bf, 65536);
    cast_bf16_kernel<<<256, 256, 0, stream>>>(Wsp, Wsp_bf, 65536);
    // 4. affinity row sums
    rowsum_kernel<<<BATCH * NSP, 256, 0, stream>>>(aff, rs);
    // 5. stoken partials (split-K=4, disjoint outputs, deterministic)
    mfma_gemm_nt<false><<<dim3(4, 4, 16), 256, 0, stream>>>(
        aff_bf, xn_cn, stoken_part, 256, 4096, 1024, 2, P, P, 65536L, nullptr, 0);
    //    reduce + cast -> stoken_bf
    reduce4_cast_kernel<<<1024, 256, 0, stream>>>(stoken_part, stoken_bf);
    // 6. st[o][m] = sum_c Wsp[o][c]*stoken[m][c] / (rs[m]+eps)
    mfma_gemm_nt<true><<<dim3(4, 4, 4), 256, 0, stream>>>(
        Wsp_bf, stoken_bf, st, 256, 256, 256, 0, 0L, 65536L, 65536L, rs, 256L);
    // 7. q/k/v: C[o][n] = sum_c W[o][c]*xn_nc[n][c]
    mfma_gemm_nt<false><<<dim3(64, 4, 4), 256, 0, stream>>>(
        Wq_bf, xn_nc, q, 4096, 256, 256, 0, 0L, P, P, nullptr, 0);
    mfma_gemm_nt<false><<<dim3(64, 4, 4), 256, 0, stream>>>(
        Wk_bf, xn_nc, k, 4096, 256, 256, 0, 0L, P, P, nullptr, 0);
    mfma_gemm_nt<false><<<dim3(64, 4, 4), 256, 0, stream>>>(
        Wv_bf, xn_nc, v, 4096, 256, 256, 0, 0L, P, P, nullptr, 0);
    // 8. stage-1 attention partials (writes pacc over dead xn buffers)
    stage1_kernel<<<dim3(16, NHEAD, BATCH), 256, 0, stream>>>(k, v, st, psum, pacc);
    // 9. merge -> s_out
    merge1_kernel<<<1024, 256, 0, stream>>>(psum, pacc, sout);
    // 10. depthwise conv into convb (aliases k, dead after stage1)
    lepe_conv_kernel<<<16384, 256, 0, stream>>>(v, lw, lb, convb);
    // 11. stage-2 attention -> d_out
    stage2_kernel<<<dim3(16, NHEAD, BATCH), 256, 0, stream>>>(q, st, sout, out);
    // 12. scrambled lepe add (LDS transpose, coalesced)
    lepe_tadd_kernel<<<dim3(16, 8, BATCH), 256, 0, stream>>>(convb, out);
}

// Round 4
// 292.716 us; speedup vs baseline: 3.1051x; 1.5260x over previous
//
#include <hip/hip_runtime.h>
#include <hip/hip_bf16.h>

#define BATCH 4
#define CCH   256
#define HWHW  4096
#define NSP   256
#define NHEAD 8
#define SCALE 0.17677669529663689f
#define PLANE 1048576L

typedef short bf16x8 __attribute__((ext_vector_type(8)));
typedef float f32x4  __attribute__((ext_vector_type(4)));

// ---------------------------------------------------------------------------
// LayerNorm over channel dim, output bf16 in [b][c][n]
__global__ __launch_bounds__(256)
void ln_kernel(const float* __restrict__ x, const float* __restrict__ w,
               const float* __restrict__ bb, __hip_bfloat16* __restrict__ xn)
{
    int id = blockIdx.x * 256 + threadIdx.x;   // B*HW = 16384
    int b = id >> 12;
    int n = id & 4095;
    long base = (long)b * CCH * HWHW + n;
    float s = 0.f, ss = 0.f;
    for (int c = 0; c < CCH; ++c) {
        float v = x[base + (long)c * HWHW];
        s += v; ss += v * v;
    }
    float mu  = s * (1.f / CCH);
    float var = ss * (1.f / CCH) - mu * mu;
    float rstd = rsqrtf(var + 1e-6f);
    for (int c = 0; c < CCH; ++c) {
        float v = x[base + (long)c * HWHW];
        xn[base + (long)c * HWHW] = __float2bfloat16((v - mu) * rstd * w[c] + bb[c]);
    }
}

// bf16 [c][n] -> [n][c] transpose (per batch)
__global__ __launch_bounds__(256)
void transpose_bf16_kernel(const __hip_bfloat16* __restrict__ in,
                           __hip_bfloat16* __restrict__ out)
{
    __shared__ __hip_bfloat16 tile[64][65];
    int n0 = blockIdx.x * 64, c0 = blockIdx.y * 64, b = blockIdx.z;
    int t = threadIdx.x;
#pragma unroll
    for (int i = 0; i < 16; ++i) {
        int idx = t + i * 256;
        int ci = idx >> 6, ni = idx & 63;
        tile[ci][ni] = in[((long)(b * CCH + c0 + ci)) * HWHW + n0 + ni];
    }
    __syncthreads();
#pragma unroll
    for (int i = 0; i < 16; ++i) {
        int idx = t + i * 256;
        int ni = idx >> 6, ci = idx & 63;
        out[((long)b * HWHW + n0 + ni) * CCH + c0 + ci] = tile[ci][ni];
    }
}

// cast the four weight matrices (each 65536 elems) in one launch
__global__ __launch_bounds__(256)
void cast_w_kernel(const float* __restrict__ Wq, const float* __restrict__ Wk,
                   const float* __restrict__ Wv, const float* __restrict__ Wsp,
                   __hip_bfloat16* __restrict__ out)
{
    int i = blockIdx.x * 256 + threadIdx.x;   // 262144
    int sel = i >> 16, idx = i & 65535;
    const float* src = (sel == 0) ? Wq : (sel == 1) ? Wk : (sel == 2) ? Wv : Wsp;
    out[i] = __float2bfloat16(src[idx]);
}

// Deterministic split-K reduction: stoken_bf[b][m][c] = bf16(sum_ch part)
__global__ __launch_bounds__(256)
void reduce4_cast_kernel(const float* __restrict__ part, __hip_bfloat16* __restrict__ out)
{
    int i = blockIdx.x * 256 + threadIdx.x;   // 262144
    int b = i >> 16, idx = i & 65535;
    long base = (long)b * 4 * 65536 + idx;
    float s = part[base] + part[base + 65536] + part[base + 131072] + part[base + 196608];
    out[i] = __float2bfloat16(s);
}

// Row sums of affinity
__global__ __launch_bounds__(256)
void rowsum_kernel(const float* __restrict__ aff, float* __restrict__ rs)
{
    int row = blockIdx.x;
    const float* p = aff + (long)row * HWHW;
    int t = threadIdx.x;
    float s = 0.f;
    for (int i = t; i < HWHW; i += 256) s += p[i];
#pragma unroll
    for (int off = 32; off; off >>= 1) s += __shfl_down(s, off, 64);
    __shared__ float red[4];
    if ((t & 63) == 0) red[t >> 6] = s;
    __syncthreads();
    if (t == 0) rs[row] = red[0] + red[1] + red[2] + red[3];
}

// ---------------------------------------------------------------------------
// bf16 MFMA NT GEMM: C[m][n] = sum_k A[m][k]*B[n][k]
// OUTK: 0=f32 out, 1=bf16 out.  ROWSCALE: divide by (rowScale[m]+1e-16).
// A32: A operand is fp32, cast inline.  z = (batch<<kShift)|kChunkIdx;
// C partials indexed by z (disjoint, deterministic).
template <int OUTK, bool ROWSCALE, bool A32>
__global__ __launch_bounds__(256)
void mfma_gemm_nt(const void* __restrict__ Aptr, const __hip_bfloat16* __restrict__ B,
                  void* __restrict__ Cptr, int N, int K, int kChunk, int kShift,
                  long aStrideZ, long bStrideZ, long cStrideZ,
                  const float* __restrict__ rowScale, long sStrideZ)
{
    __shared__ __hip_bfloat16 Asm[4 * 64 * 8];
    __shared__ __hip_bfloat16 Bsm[4 * 64 * 8];
    int z = blockIdx.z;
    int b = z >> kShift;
    int ch = z & ((1 << kShift) - 1);
    int t = threadIdx.x;
    int lane = t & 63, w = t >> 6;
    int l15 = lane & 15, quad = lane >> 4;
    int Mt = blockIdx.y * 64, Nt = blockIdx.x * 64;

    const float* aSrcF = A32 ? ((const float*)Aptr + b * aStrideZ + (long)ch * kChunk
                                + (long)(Mt + w * 16 + l15) * K + quad * 8) : nullptr;
    const __hip_bfloat16* aSrcB = A32 ? nullptr :
        ((const __hip_bfloat16*)Aptr + b * aStrideZ + (long)ch * kChunk
         + (long)(Mt + w * 16 + l15) * K + quad * 8);
    const __hip_bfloat16* bSrc = B + b * bStrideZ + (long)ch * kChunk
        + (long)(Nt + w * 16 + l15) * K + quad * 8;
    __hip_bfloat16* aDst = &Asm[t * 8];
    __hip_bfloat16* bDst = &Bsm[t * 8];

    f32x4 acc00 = {0.f,0.f,0.f,0.f}, acc01 = acc00, acc10 = acc00, acc11 = acc00;
    int wm = (w & 1) * 2, wn = (w >> 1) * 2;

    for (int k0 = 0; k0 < kChunk; k0 += 32) {
        if (A32) {
            float4 f0 = ((const float4*)aSrcF)[0];
            float4 f1 = ((const float4*)aSrcF)[1];
            __hip_bfloat16 tmp[8];
            tmp[0]=__float2bfloat16(f0.x); tmp[1]=__float2bfloat16(f0.y);
            tmp[2]=__float2bfloat16(f0.z); tmp[3]=__float2bfloat16(f0.w);
            tmp[4]=__float2bfloat16(f1.x); tmp[5]=__float2bfloat16(f1.y);
            tmp[6]=__float2bfloat16(f1.z); tmp[7]=__float2bfloat16(f1.w);
            *(int4*)aDst = *(const int4*)tmp;
            aSrcF += 32;
        } else {
            *(int4*)aDst = *(const int4*)aSrcB;
            aSrcB += 32;
        }
        *(int4*)bDst = *(const int4*)bSrc;
        bSrc += 32;
        __syncthreads();
        bf16x8 a0 = ((const bf16x8*)Asm)[wm * 64 + lane];
        bf16x8 a1 = ((const bf16x8*)Asm)[(wm + 1) * 64 + lane];
        bf16x8 b0 = ((const bf16x8*)Bsm)[wn * 64 + lane];
        bf16x8 b1 = ((const bf16x8*)Bsm)[(wn + 1) * 64 + lane];
        acc00 = __builtin_amdgcn_mfma_f32_16x16x32_bf16(a0, b0, acc00, 0, 0, 0);
        acc01 = __builtin_amdgcn_mfma_f32_16x16x32_bf16(a0, b1, acc01, 0, 0, 0);
        acc10 = __builtin_amdgcn_mfma_f32_16x16x32_bf16(a1, b0, acc10, 0, 0, 0);
        acc11 = __builtin_amdgcn_mfma_f32_16x16x32_bf16(a1, b1, acc11, 0, 0, 0);
        __syncthreads();
    }
    f32x4 accs[2][2] = {{acc00, acc01}, {acc10, acc11}};
#pragma unroll
    for (int i = 0; i < 2; ++i)
#pragma unroll
        for (int j = 0; j < 2; ++j)
#pragma unroll
            for (int r = 0; r < 4; ++r) {
                int m = Mt + (wm + i) * 16 + quad * 4 + r;
                int n = Nt + (wn + j) * 16 + l15;
                float val = accs[i][j][r];
                if (ROWSCALE) val /= (rowScale[(long)b * sStrideZ + m] + 1e-16f);
                long off = (long)z * cStrideZ + (long)m * N + n;
                if (OUTK == 0) ((float*)Cptr)[off] = val;
                else ((__hip_bfloat16*)Cptr)[off] = __float2bfloat16(val);
            }
}

// ---------------------------------------------------------------------------
// Stage-1 MFMA attention partials.  Per block: one (b,h), 256-pixel chunk.
// GEMM1: E[m][n]=exp(scale*st.k), GEMM2 (with ones-row): O[m][0..31]=V.E,
// O[m][32]=denominator partial.  grid (16 chunks, 32 bh).
__global__ __launch_bounds__(256)
void stage1_mfma(const __hip_bfloat16* __restrict__ k_nc,
                 const __hip_bfloat16* __restrict__ v_cn,
                 const __hip_bfloat16* __restrict__ st_md,
                 float* __restrict__ opart)
{
    __shared__ __hip_bfloat16 Es[256 * 72];    // E[m][64 n-cols], pitch 72
    __shared__ __hip_bfloat16 sts[256 * 40];   // st[m][32 d], pitch 40
    const int chunk = blockIdx.x, bh = blockIdx.y;
    const int b = bh >> 3, h = bh & 7;
    const int t = threadIdx.x, lane = t & 63, w = t >> 6;
    const int l15 = lane & 15, quad = lane >> 4;
    const int n0 = chunk * 256;

    {   // stage st rows (one row per thread)
        const int4* src = (const int4*)(st_md + ((long)(b * 256 + t)) * 256 + h * 32);
        int4* dst = (int4*)&sts[t * 40];
        dst[0] = src[0]; dst[1] = src[1]; dst[2] = src[2]; dst[3] = src[3];
    }
    __syncthreads();
    bf16x8 afrag[16];
#pragma unroll
    for (int mt = 0; mt < 16; ++mt)
        afrag[mt] = *(const bf16x8*)&sts[(mt * 16 + l15) * 40 + quad * 8];
    bf16x8 onesf;
    { short o = (l15 == 0) ? (short)0x3F80 : (short)0;
      onesf = bf16x8{o, o, o, o, o, o, o, o}; }

    f32x4 occ[4][3];
#pragma unroll
    for (int i = 0; i < 4; ++i)
#pragma unroll
        for (int j = 0; j < 3; ++j) occ[i][j] = f32x4{0.f,0.f,0.f,0.f};

    for (int sub = 0; sub < 4; ++sub) {
        const int nbase = n0 + sub * 64;
        // GEMM1: this wave covers n-cols [16w,16w+16)
        bf16x8 kf = *(const bf16x8*)(k_nc + ((long)b * 4096 + nbase + 16 * w + l15) * 256 + h * 32 + quad * 8);
#pragma unroll
        for (int mt = 0; mt < 16; ++mt) {
            f32x4 s = __builtin_amdgcn_mfma_f32_16x16x32_bf16(afrag[mt], kf, f32x4{0.f,0.f,0.f,0.f}, 0, 0, 0);
#pragma unroll
            for (int r = 0; r < 4; ++r)
                Es[(mt * 16 + quad * 4 + r) * 72 + 16 * w + l15] =
                    __float2bfloat16(__expf(s[r] * SCALE));
        }
        __syncthreads();
        // GEMM2: wave w owns m in [64w, 64w+64)
#pragma unroll
        for (int ks = 0; ks < 2; ++ks) {
            bf16x8 bf0 = *(const bf16x8*)(v_cn + ((long)(b * 256 + h * 32 + l15)) * 4096 + nbase + ks * 32 + quad * 8);
            bf16x8 bf1 = *(const bf16x8*)(v_cn + ((long)(b * 256 + h * 32 + 16 + l15)) * 4096 + nbase + ks * 32 + quad * 8);
#pragma unroll
            for (int mi = 0; mi < 4; ++mi) {
                bf16x8 af = *(const bf16x8*)&Es[(64 * w + mi * 16 + l15) * 72 + ks * 32 + quad * 8];
                occ[mi][0] = __builtin_amdgcn_mfma_f32_16x16x32_bf16(af, bf0, occ[mi][0], 0, 0, 0);
                occ[mi][1] = __builtin_amdgcn_mfma_f32_16x16x32_bf16(af, bf1, occ[mi][1], 0, 0, 0);
                occ[mi][2] = __builtin_amdgcn_mfma_f32_16x16x32_bf16(af, onesf, occ[mi][2], 0, 0, 0);
            }
        }
        __syncthreads();
    }
    const long ob = ((long)chunk * 32 + bh) * 256 * 33;
#pragma unroll
    for (int mi = 0; mi < 4; ++mi)
#pragma unroll
        for (int jt = 0; jt < 3; ++jt) {
            if (jt == 2 && l15 != 0) continue;
            int col = jt * 16 + l15;
#pragma unroll
            for (int r = 0; r < 4; ++r) {
                int m = 64 * w + mi * 16 + quad * 4 + r;
                opart[ob + (long)m * 33 + col] = occ[mi][jt][r];
            }
        }
}

// Merge stage-1 partials -> sout_bf[bh][d][m]
__global__ __launch_bounds__(256)
void merge1_kernel(const float* __restrict__ opart, __hip_bfloat16* __restrict__ sout)
{
    int t = blockIdx.x * 256 + threadIdx.x;   // 262144
    int m = t & 255;
    int d = (t >> 8) & 31;
    int bh = t >> 13;
    float num = 0.f, den = 0.f;
    for (int ch = 0; ch < 16; ++ch) {
        long base = (((long)ch * 32 + bh) * 256 + m) * 33;
        num += opart[base + d];
        den += opart[base + 32];
    }
    sout[(long)bh * 8192 + d * 256 + m] = __float2bfloat16(num / den);
}

// ---------------------------------------------------------------------------
// Stage-2 MFMA attention.  Per block: one (b,h), 256-pixel chunk.
// GEMM1: E2[n][m]=exp(scale*q.st); GEMM2 (ones-row): out[n][d]=s_out.E2/denom.
// Writes final out[b][c][n] (coalesced via LDS transpose).
__global__ __launch_bounds__(256)
void stage2_mfma(const __hip_bfloat16* __restrict__ q_nc,
                 const __hip_bfloat16* __restrict__ st_md,
                 const __hip_bfloat16* __restrict__ sout_bf,
                 float* __restrict__ out)
{
    __shared__ __hip_bfloat16 Es2[64 * 264];   // E2[n][256 m], pitch 264
    __shared__ __hip_bfloat16 sts[256 * 40];
    __shared__ __hip_bfloat16 sos[32 * 264];   // s_out[d][m], pitch 264
    __shared__ float o_t[32 * 68];             // out-tile [d][64 n], pitch 68
    const int chunk = blockIdx.x, bh = blockIdx.y;
    const int b = bh >> 3, h = bh & 7;
    const int t = threadIdx.x, lane = t & 63, w = t >> 6;
    const int l15 = lane & 15, quad = lane >> 4;
    const int n0 = chunk * 256;

    {   // stage st
        const int4* src = (const int4*)(st_md + ((long)(b * 256 + t)) * 256 + h * 32);
        int4* dst = (int4*)&sts[t * 40];
        dst[0] = src[0]; dst[1] = src[1]; dst[2] = src[2]; dst[3] = src[3];
    }
    {   // stage s_out
        int row = t >> 3, seg = t & 7;
        const int4* src = (const int4*)(sout_bf + (long)bh * 8192 + row * 256 + seg * 32);
        int4* dst = (int4*)&sos[row * 264 + seg * 32];
        dst[0] = src[0]; dst[1] = src[1]; dst[2] = src[2]; dst[3] = src[3];
    }
    __syncthreads();
    bf16x8 stfrag[4];
#pragma unroll
    for (int mt = 0; mt < 4; ++mt)
        stfrag[mt] = *(const bf16x8*)&sts[(64 * w + mt * 16 + l15) * 40 + quad * 8];
    bf16x8 onesf;
    { short o = (l15 == 0) ? (short)0x3F80 : (short)0;
      onesf = bf16x8{o, o, o, o, o, o, o, o}; }

    for (int sub = 0; sub < 4; ++sub) {
        const int nbase = n0 + sub * 64;
        // GEMM1: wave computes m in [64w,64w+64) for all 64 n of this subtile
#pragma unroll
        for (int nt = 0; nt < 4; ++nt) {
            bf16x8 qf = *(const bf16x8*)(q_nc + ((long)b * 4096 + nbase + nt * 16 + l15) * 256 + h * 32 + quad * 8);
#pragma unroll
            for (int mt = 0; mt < 4; ++mt) {
                f32x4 s = __builtin_amdgcn_mfma_f32_16x16x32_bf16(qf, stfrag[mt], f32x4{0.f,0.f,0.f,0.f}, 0, 0, 0);
#pragma unroll
                for (int r = 0; r < 4; ++r)
                    Es2[(nt * 16 + quad * 4 + r) * 264 + 64 * w + mt * 16 + l15] =
                        __float2bfloat16(__expf(s[r] * SCALE));
            }
        }
        __syncthreads();
        // GEMM2: wave w -> n-tile w (16 pixels), K = 256 m
        f32x4 o0 = {0.f,0.f,0.f,0.f}, o1 = o0, o2 = o0;
#pragma unroll
        for (int ks = 0; ks < 8; ++ks) {
            bf16x8 af = *(const bf16x8*)&Es2[(16 * w + l15) * 264 + ks * 32 + quad * 8];
            bf16x8 b0 = *(const bf16x8*)&sos[(l15) * 264 + ks * 32 + quad * 8];
            bf16x8 b1 = *(const bf16x8*)&sos[(16 + l15) * 264 + ks * 32 + quad * 8];
            o0 = __builtin_amdgcn_mfma_f32_16x16x32_bf16(af, b0, o0, 0, 0, 0);
            o1 = __builtin_amdgcn_mfma_f32_16x16x32_bf16(af, b1, o1, 0, 0, 0);
            o2 = __builtin_amdgcn_mfma_f32_16x16x32_bf16(af, onesf, o2, 0, 0, 0);
        }
        __syncthreads();
#pragma unroll
        for (int r = 0; r < 4; ++r) {
            float den = __shfl(o2[r], lane & 48);
            float inv = 1.f / den;
            o_t[(l15) * 68 + 16 * w + quad * 4 + r]      = o0[r] * inv;
            o_t[(16 + l15) * 68 + 16 * w + quad * 4 + r] = o1[r] * inv;
        }
        __syncthreads();
        {   // coalesced store of 32 rows x 64 cols
            int row = t >> 3, coff = (t & 7) * 8;
            long gb = ((long)(b * 256 + h * 32 + row)) * 4096 + nbase + coff;
            const float* sp = &o_t[row * 68 + coff];
            *(float2*)(out + gb)     = *(const float2*)(sp);
            *(float2*)(out + gb + 2) = *(const float2*)(sp + 2);
            *(float2*)(out + gb + 4) = *(const float2*)(sp + 4);
            *(float2*)(out + gb + 6) = *(const float2*)(sp + 6);
        }
        __syncthreads();
    }
}

// ---------------------------------------------------------------------------
// Depthwise 3x3 conv on v(x) + bias (bf16 in/out)
__global__ __launch_bounds__(256)
void lepe_conv_kernel(const __hip_bfloat16* __restrict__ vx, const float* __restrict__ lw,
                      const float* __restrict__ lb, __hip_bfloat16* __restrict__ outc)
{
    int idx = blockIdx.x * 256 + threadIdx.x;   // 4194304
    int n = idx & 4095;
    int c = (idx >> 12) & 255;
    int b = idx >> 20;
    int hh = n >> 6, ww = n & 63;
    const __hip_bfloat16* src = vx + ((long)(b * CCH + c) << 12);
    float acc = lb[c];
#pragma unroll
    for (int kh = 0; kh < 3; ++kh) {
        int h2 = hh + kh - 1;
        if ((unsigned)h2 < 64u) {
#pragma unroll
            for (int kw = 0; kw < 3; ++kw) {
                int w2 = ww + kw - 1;
                if ((unsigned)w2 < 64u)
                    acc += (float)src[h2 * 64 + w2] * lw[c * 9 + kh * 3 + kw];
            }
        }
    }
    outc[idx] = __float2bfloat16(acc);
}

// Scrambled lepe add: out[b,c2,n2] += conv[b][c'][n']
__global__ __launch_bounds__(256)
void lepe_tadd_kernel(const __hip_bfloat16* __restrict__ convb, float* __restrict__ out)
{
    __shared__ float tile[256][33];
    int n0 = blockIdx.x * 256;
    int c0 = blockIdx.y * 32;
    int b  = blockIdx.z;
    int t = threadIdx.x;
#pragma unroll
    for (int i = 0; i < 32; ++i) {
        int idx = t + i * 256;
        int ci = idx >> 8, nl = idx & 255;
        tile[nl][ci] = (float)convb[((long)(b * CCH + c0 + ci) << 12) + n0 + nl];
    }
    __syncthreads();
#pragma unroll
    for (int i = 0; i < 32; ++i) {
        int idx = t + i * 256;
        int nl = idx >> 5, ci = idx & 31;
        int c2 = (n0 + nl) >> 4;
        int n2 = (nl & 15) * 256 + c0 + ci;
        out[((long)(b * CCH + c2) << 12) + n2] += tile[nl][ci];
    }
}

// ---------------------------------------------------------------------------
extern "C" void kernel_launch(void* const* d_in, const int* in_sizes, int n_in,
                              void* d_out, int out_size, void* d_ws, size_t ws_size,
                              hipStream_t stream)
{
    const float* x    = (const float*)d_in[0];
    const float* aff  = (const float*)d_in[1];
    const float* nw   = (const float*)d_in[2];
    const float* nb   = (const float*)d_in[3];
    const float* Wq   = (const float*)d_in[4];
    const float* Wk   = (const float*)d_in[5];
    const float* Wv   = (const float*)d_in[6];
    const float* Wsp  = (const float*)d_in[7];
    const float* lw   = (const float*)d_in[8];
    const float* lb   = (const float*)d_in[9];
    float* out = (float*)d_out;

    float* ws = (float*)d_ws;
    const long P = PLANE;
    __hip_bfloat16* q_nc  = (__hip_bfloat16*)(ws);          // [b][n][c] bf16
    __hip_bfloat16* k_nc  = (__hip_bfloat16*)(ws + 2 * P);  // [b][n][c] bf16
    __hip_bfloat16* v_cn  = (__hip_bfloat16*)(ws + 4 * P);  // [b][c][n] bf16
    __hip_bfloat16* xn_cn = (__hip_bfloat16*)(ws + 6 * P);
    __hip_bfloat16* xn_nc = (__hip_bfloat16*)(ws + 8 * P);
    float* stoken_part = ws + 10 * P;                       // 16 x 65536 f32
    float* opart       = ws + 11 * P;                       // 16*32*256*33 f32
    float* tail        = ws + 11 * P + 4325376;
    __hip_bfloat16* Wq_bf  = (__hip_bfloat16*)tail;
    __hip_bfloat16* Wk_bf  = Wq_bf + 65536;
    __hip_bfloat16* Wv_bf  = Wk_bf + 65536;
    __hip_bfloat16* Wsp_bf = Wv_bf + 65536;
    __hip_bfloat16* stoken_bf = (__hip_bfloat16*)(tail + 131072);
    __hip_bfloat16* st_md     = (__hip_bfloat16*)(tail + 262144);  // [b][m][c] bf16
    __hip_bfloat16* sout_bf   = (__hip_bfloat16*)(tail + 393216);  // [bh][d][m] bf16
    float* rs = tail + 524288;                                      // 1024
    __hip_bfloat16* convb = k_nc;   // alias: k dead after stage1

    // 1. LayerNorm -> xn_cn
    ln_kernel<<<64, 256, 0, stream>>>(x, nw, nb, xn_cn);
    // 2. transpose -> xn_nc
    transpose_bf16_kernel<<<dim3(64, 4, BATCH), 256, 0, stream>>>(xn_cn, xn_nc);
    // 3. weight casts (one launch)
    cast_w_kernel<<<1024, 256, 0, stream>>>(Wq, Wk, Wv, Wsp, Wq_bf);
    // 4. affinity row sums
    rowsum_kernel<<<BATCH * NSP, 256, 0, stream>>>(aff, rs);
    // 5. stoken partials: A=aff (fp32, inline cast), B=xn_cn, split-K=4
    mfma_gemm_nt<0, false, true><<<dim3(4, 4, 16), 256, 0, stream>>>(
        aff, xn_cn, stoken_part, 256, 4096, 1024, 2, P, P, 65536L, nullptr, 0);
    reduce4_cast_kernel<<<1024, 256, 0, stream>>>(stoken_part, stoken_bf);
    // 6. st_md[b][m][o] = stoken[m][.]·Wsp[o][.] / (rs[m]+eps)   (bf16 out)
    mfma_gemm_nt<1, true, false><<<dim3(4, 4, 4), 256, 0, stream>>>(
        stoken_bf, Wsp_bf, st_md, 256, 256, 256, 0, 65536L, 0L, 65536L, rs, 256L);
    // 7. q_nc[b][n][o] = xn_nc[n][.]·Wq[o][.]
    mfma_gemm_nt<1, false, false><<<dim3(4, 64, 4), 256, 0, stream>>>(
        xn_nc, Wq_bf, q_nc, 256, 256, 256, 0, P, 0L, P, nullptr, 0);
    mfma_gemm_nt<1, false, false><<<dim3(4, 64, 4), 256, 0, stream>>>(
        xn_nc, Wk_bf, k_nc, 256, 256, 256, 0, P, 0L, P, nullptr, 0);
    //    v_cn[b][o][n] = Wv[o][.]·xn_nc[n][.]
    mfma_gemm_nt<1, false, false><<<dim3(64, 4, 4), 256, 0, stream>>>(
        Wv_bf, xn_nc, v_cn, 4096, 256, 256, 0, 0L, P, P, nullptr, 0);
    // 8. stage-1 MFMA attention partials
    stage1_mfma<<<dim3(16, 32), 256, 0, stream>>>(k_nc, v_cn, st_md, opart);
    // 9. merge -> sout_bf
    merge1_kernel<<<1024, 256, 0, stream>>>(opart, sout_bf);
    // 10. depthwise conv -> convb (aliases k_nc)
    lepe_conv_kernel<<<16384, 256, 0, stream>>>(v_cn, lw, lb, convb);
    // 11. stage-2 MFMA attention -> d_out
    stage2_mfma<<<dim3(16, 32), 256, 0, stream>>>(q_nc, st_md, sout_bf, out);
    // 12. scrambled lepe add
    lepe_tadd_kernel<<<dim3(16, 8, BATCH), 256, 0, stream>>>(convb, out);
}

// Round 5
// 278.828 us; speedup vs baseline: 3.2598x; 1.0498x over previous
//
#include <hip/hip_runtime.h>
#include <hip/hip_bf16.h>

#define BATCH 4
#define CCH   256
#define HWHW  4096
#define NSP   256
#define NHEAD 8
#define SCALE 0.17677669529663689f
#define PLANE 1048576L

typedef short bf16x8 __attribute__((ext_vector_type(8)));
typedef float f32x4  __attribute__((ext_vector_type(4)));

// ---------------------------------------------------------------------------
// Fused LayerNorm: writes xn_cn [b][c][n] AND xn_nc [b][n][c] (bf16).
// 256 blocks x 256 threads; block = 64 pixels, thread = (cq 4) x (p 64).
__global__ __launch_bounds__(256)
void ln_fused_kernel(const float* __restrict__ x, const float* __restrict__ w,
                     const float* __restrict__ bb,
                     __hip_bfloat16* __restrict__ xn_cn,
                     __hip_bfloat16* __restrict__ xn_nc)
{
    __shared__ float xs[256][64];      // [c][p]
    __shared__ float ps[4][64], pss[4][64], mus[64], rstds[64];
    __shared__ float wls[256], bls[256];
    int blk = blockIdx.x;              // 256
    int b = blk >> 6;
    int n0 = (blk & 63) * 64;
    int t = threadIdx.x, p = t & 63, cq = t >> 6;
    wls[t] = w[t]; bls[t] = bb[t];
    long base = (long)b * CCH * HWHW + n0 + p;
    float s = 0.f, ss = 0.f;
#pragma unroll 8
    for (int i = 0; i < 64; ++i) {
        int c = cq * 64 + i;
        float v = x[base + (long)c * HWHW];
        xs[c][p] = v; s += v; ss += v * v;
    }
    ps[cq][p] = s; pss[cq][p] = ss;
    __syncthreads();
    if (cq == 0) {
        float S  = ps[0][p] + ps[1][p] + ps[2][p] + ps[3][p];
        float SS = pss[0][p] + pss[1][p] + pss[2][p] + pss[3][p];
        float mu = S * (1.f / 256.f);
        float var = SS * (1.f / 256.f) - mu * mu;
        mus[p] = mu; rstds[p] = rsqrtf(var + 1e-6f);
    }
    __syncthreads();
    float mu = mus[p], rstd = rstds[p];
#pragma unroll
    for (int c8 = 0; c8 < 8; ++c8) {
        short pack[8];
#pragma unroll
        for (int j = 0; j < 8; ++j) {
            int c = cq * 64 + c8 * 8 + j;
            float v = (xs[c][p] - mu) * rstd * wls[c] + bls[c];
            __hip_bfloat16 bv = __float2bfloat16(v);
            xn_cn[(long)(b * CCH + c) * HWHW + n0 + p] = bv;
            pack[j] = *(short*)&bv;
        }
        *(int4*)(xn_nc + ((long)b * HWHW + n0 + p) * CCH + cq * 64 + c8 * 8) = *(int4*)pack;
    }
}

// ---------------------------------------------------------------------------
// Combined prep: blocks 0..1023 = affinity row sums; 1024..2047 = weight casts
__global__ __launch_bounds__(256)
void prep_kernel(const float* __restrict__ aff,
                 const float* __restrict__ Wq, const float* __restrict__ Wk,
                 const float* __restrict__ Wv, const float* __restrict__ Wsp,
                 __hip_bfloat16* __restrict__ wbf, float* __restrict__ rs)
{
    int bid = blockIdx.x;
    int t = threadIdx.x;
    if (bid < 1024) {
        const float* p = aff + (long)bid * HWHW;
        float s = 0.f;
        for (int i = t; i < HWHW; i += 256) s += p[i];
#pragma unroll
        for (int off = 32; off; off >>= 1) s += __shfl_down(s, off, 64);
        __shared__ float red[4];
        if ((t & 63) == 0) red[t >> 6] = s;
        __syncthreads();
        if (t == 0) rs[bid] = red[0] + red[1] + red[2] + red[3];
    } else {
        int i = (bid - 1024) * 256 + t;   // 262144
        int sel = i >> 16, idx = i & 65535;
        const float* src = (sel == 0) ? Wq : (sel == 1) ? Wk : (sel == 2) ? Wv : Wsp;
        wbf[i] = __float2bfloat16(src[idx]);
    }
}

// Deterministic split-K(8) reduction -> stoken_bf[b][m][c]
__global__ __launch_bounds__(256)
void reduce8_cast_kernel(const float* __restrict__ part, __hip_bfloat16* __restrict__ out)
{
    int i = blockIdx.x * 256 + threadIdx.x;   // 262144
    int b = i >> 16, idx = i & 65535;
    long base = (long)b * 8 * 65536 + idx;
    float s = 0.f;
#pragma unroll
    for (int ch = 0; ch < 8; ++ch) s += part[base + (long)ch * 65536];
    out[i] = __float2bfloat16(s);
}

// ---------------------------------------------------------------------------
// bf16 MFMA NT GEMM: C[m][n] = sum_k A[m][k]*B[n][k]
// OUTK: 0=f32 out, 1=bf16 out.  ROWSCALE: /(rowScale[m]+1e-16).  A32: fp32 A.
template <int OUTK, bool ROWSCALE, bool A32>
__global__ __launch_bounds__(256)
void mfma_gemm_nt(const void* __restrict__ Aptr, const __hip_bfloat16* __restrict__ B,
                  void* __restrict__ Cptr, int N, int K, int kChunk, int kShift,
                  long aStrideZ, long bStrideZ, long cStrideZ,
                  const float* __restrict__ rowScale, long sStrideZ)
{
    __shared__ __hip_bfloat16 Asm[4 * 64 * 8];
    __shared__ __hip_bfloat16 Bsm[4 * 64 * 8];
    int z = blockIdx.z;
    int b = z >> kShift;
    int ch = z & ((1 << kShift) - 1);
    int t = threadIdx.x;
    int lane = t & 63, w = t >> 6;
    int l15 = lane & 15, quad = lane >> 4;
    int Mt = blockIdx.y * 64, Nt = blockIdx.x * 64;

    const float* aSrcF = A32 ? ((const float*)Aptr + b * aStrideZ + (long)ch * kChunk
                                + (long)(Mt + w * 16 + l15) * K + quad * 8) : nullptr;
    const __hip_bfloat16* aSrcB = A32 ? nullptr :
        ((const __hip_bfloat16*)Aptr + b * aStrideZ + (long)ch * kChunk
         + (long)(Mt + w * 16 + l15) * K + quad * 8);
    const __hip_bfloat16* bSrc = B + b * bStrideZ + (long)ch * kChunk
        + (long)(Nt + w * 16 + l15) * K + quad * 8;
    __hip_bfloat16* aDst = &Asm[t * 8];
    __hip_bfloat16* bDst = &Bsm[t * 8];

    f32x4 acc00 = {0.f,0.f,0.f,0.f}, acc01 = acc00, acc10 = acc00, acc11 = acc00;
    int wm = (w & 1) * 2, wn = (w >> 1) * 2;

    for (int k0 = 0; k0 < kChunk; k0 += 32) {
        if (A32) {
            float4 f0 = ((const float4*)aSrcF)[0];
            float4 f1 = ((const float4*)aSrcF)[1];
            __hip_bfloat16 tmp[8];
            tmp[0]=__float2bfloat16(f0.x); tmp[1]=__float2bfloat16(f0.y);
            tmp[2]=__float2bfloat16(f0.z); tmp[3]=__float2bfloat16(f0.w);
            tmp[4]=__float2bfloat16(f1.x); tmp[5]=__float2bfloat16(f1.y);
            tmp[6]=__float2bfloat16(f1.z); tmp[7]=__float2bfloat16(f1.w);
            *(int4*)aDst = *(const int4*)tmp;
            aSrcF += 32;
        } else {
            *(int4*)aDst = *(const int4*)aSrcB;
            aSrcB += 32;
        }
        *(int4*)bDst = *(const int4*)bSrc;
        bSrc += 32;
        __syncthreads();
        bf16x8 a0 = ((const bf16x8*)Asm)[wm * 64 + lane];
        bf16x8 a1 = ((const bf16x8*)Asm)[(wm + 1) * 64 + lane];
        bf16x8 b0 = ((const bf16x8*)Bsm)[wn * 64 + lane];
        bf16x8 b1 = ((const bf16x8*)Bsm)[(wn + 1) * 64 + lane];
        acc00 = __builtin_amdgcn_mfma_f32_16x16x32_bf16(a0, b0, acc00, 0, 0, 0);
        acc01 = __builtin_amdgcn_mfma_f32_16x16x32_bf16(a0, b1, acc01, 0, 0, 0);
        acc10 = __builtin_amdgcn_mfma_f32_16x16x32_bf16(a1, b0, acc10, 0, 0, 0);
        acc11 = __builtin_amdgcn_mfma_f32_16x16x32_bf16(a1, b1, acc11, 0, 0, 0);
        __syncthreads();
    }
    f32x4 accs[2][2] = {{acc00, acc01}, {acc10, acc11}};
#pragma unroll
    for (int i = 0; i < 2; ++i)
#pragma unroll
        for (int j = 0; j < 2; ++j)
#pragma unroll
            for (int r = 0; r < 4; ++r) {
                int m = Mt + (wm + i) * 16 + quad * 4 + r;
                int n = Nt + (wn + j) * 16 + l15;
                float val = accs[i][j][r];
                if (ROWSCALE) val /= (rowScale[(long)b * sStrideZ + m] + 1e-16f);
                long off = (long)z * cStrideZ + (long)m * N + n;
                if (OUTK == 0) ((float*)Cptr)[off] = val;
                else ((__hip_bfloat16*)Cptr)[off] = __float2bfloat16(val);
            }
}

// ---------------------------------------------------------------------------
// Stage-1 MFMA attention partials.  k lives in qk_nc at column offset 256.
__global__ __launch_bounds__(256)
void stage1_mfma(const __hip_bfloat16* __restrict__ qk_nc,
                 const __hip_bfloat16* __restrict__ v_cn,
                 const __hip_bfloat16* __restrict__ st_md,
                 float* __restrict__ opart)
{
    __shared__ __hip_bfloat16 Es[256 * 72];
    __shared__ __hip_bfloat16 sts[256 * 40];
    const int chunk = blockIdx.x, bh = blockIdx.y;
    const int b = bh >> 3, h = bh & 7;
    const int t = threadIdx.x, lane = t & 63, w = t >> 6;
    const int l15 = lane & 15, quad = lane >> 4;
    const int n0 = chunk * 256;

    {
        const int4* src = (const int4*)(st_md + ((long)(b * 256 + t)) * 256 + h * 32);
        int4* dst = (int4*)&sts[t * 40];
        dst[0] = src[0]; dst[1] = src[1]; dst[2] = src[2]; dst[3] = src[3];
    }
    __syncthreads();
    bf16x8 afrag[16];
#pragma unroll
    for (int mt = 0; mt < 16; ++mt)
        afrag[mt] = *(const bf16x8*)&sts[(mt * 16 + l15) * 40 + quad * 8];
    bf16x8 onesf;
    { short o = (l15 == 0) ? (short)0x3F80 : (short)0;
      onesf = bf16x8{o, o, o, o, o, o, o, o}; }

    f32x4 occ[4][3];
#pragma unroll
    for (int i = 0; i < 4; ++i)
#pragma unroll
        for (int j = 0; j < 3; ++j) occ[i][j] = f32x4{0.f,0.f,0.f,0.f};

    for (int sub = 0; sub < 4; ++sub) {
        const int nbase = n0 + sub * 64;
        bf16x8 kf = *(const bf16x8*)(qk_nc + ((long)b * 4096 + nbase + 16 * w + l15) * 512 + 256 + h * 32 + quad * 8);
#pragma unroll
        for (int mt = 0; mt < 16; ++mt) {
            f32x4 s = __builtin_amdgcn_mfma_f32_16x16x32_bf16(afrag[mt], kf, f32x4{0.f,0.f,0.f,0.f}, 0, 0, 0);
#pragma unroll
            for (int r = 0; r < 4; ++r)
                Es[(mt * 16 + quad * 4 + r) * 72 + 16 * w + l15] =
                    __float2bfloat16(__expf(s[r] * SCALE));
        }
        __syncthreads();
#pragma unroll
        for (int ks = 0; ks < 2; ++ks) {
            bf16x8 bf0 = *(const bf16x8*)(v_cn + ((long)(b * 256 + h * 32 + l15)) * 4096 + nbase + ks * 32 + quad * 8);
            bf16x8 bf1 = *(const bf16x8*)(v_cn + ((long)(b * 256 + h * 32 + 16 + l15)) * 4096 + nbase + ks * 32 + quad * 8);
#pragma unroll
            for (int mi = 0; mi < 4; ++mi) {
                bf16x8 af = *(const bf16x8*)&Es[(64 * w + mi * 16 + l15) * 72 + ks * 32 + quad * 8];
                occ[mi][0] = __builtin_amdgcn_mfma_f32_16x16x32_bf16(af, bf0, occ[mi][0], 0, 0, 0);
                occ[mi][1] = __builtin_amdgcn_mfma_f32_16x16x32_bf16(af, bf1, occ[mi][1], 0, 0, 0);
                occ[mi][2] = __builtin_amdgcn_mfma_f32_16x16x32_bf16(af, onesf, occ[mi][2], 0, 0, 0);
            }
        }
        __syncthreads();
    }
    const long ob = ((long)chunk * 32 + bh) * 256 * 33;
#pragma unroll
    for (int mi = 0; mi < 4; ++mi)
#pragma unroll
        for (int jt = 0; jt < 3; ++jt) {
            if (jt == 2 && l15 != 0) continue;
            int col = jt * 16 + l15;
#pragma unroll
            for (int r = 0; r < 4; ++r) {
                int m = 64 * w + mi * 16 + quad * 4 + r;
                opart[ob + (long)m * 33 + col] = occ[mi][jt][r];
            }
        }
}

// Merge stage-1 partials -> sout_bf[bh][d][m]
__global__ __launch_bounds__(256)
void merge1_kernel(const float* __restrict__ opart, __hip_bfloat16* __restrict__ sout)
{
    int t = blockIdx.x * 256 + threadIdx.x;   // 262144
    int m = t & 255;
    int d = (t >> 8) & 31;
    int bh = t >> 13;
    float num = 0.f, den = 0.f;
    for (int ch = 0; ch < 16; ++ch) {
        long base = (((long)ch * 32 + bh) * 256 + m) * 33;
        num += opart[base + d];
        den += opart[base + 32];
    }
    sout[(long)bh * 8192 + d * 256 + m] = __float2bfloat16(num / den);
}

// ---------------------------------------------------------------------------
// Depthwise 3x3 conv + scramble-transpose: writes lepe in FINAL [b][c][n]
// layout (bf16):  lepe_cn[b][sp>>4][(sp&15)*256 + c'] = conv[b][c'][sp]
__global__ __launch_bounds__(256)
void lepe_conv_t_kernel(const __hip_bfloat16* __restrict__ v_cn,
                        const float* __restrict__ lw, const float* __restrict__ lb,
                        __hip_bfloat16* __restrict__ lepe_cn)
{
    __shared__ float tile[256][33];
    int n0 = blockIdx.x * 256;   // conv spatial tile
    int c0 = blockIdx.y * 32;    // conv channel tile
    int b  = blockIdx.z;
    int t = threadIdx.x;
    int ci = t & 31, g = t >> 5;
    int c = c0 + ci;
    const __hip_bfloat16* src = v_cn + ((long)(b * CCH + c) << 12);
    float wr[9];
#pragma unroll
    for (int j = 0; j < 9; ++j) wr[j] = lw[c * 9 + j];
    float bias = lb[c];
#pragma unroll 4
    for (int i = 0; i < 32; ++i) {
        int nl = g * 32 + i;
        int n = n0 + nl;
        int hh = n >> 6, ww = n & 63;
        float acc = bias;
#pragma unroll
        for (int kh = 0; kh < 3; ++kh) {
            int h2 = hh + kh - 1;
            if ((unsigned)h2 < 64u) {
#pragma unroll
                for (int kw = 0; kw < 3; ++kw) {
                    int w2 = ww + kw - 1;
                    if ((unsigned)w2 < 64u)
                        acc += (float)src[h2 * 64 + w2] * wr[kh * 3 + kw];
                }
            }
        }
        tile[nl][ci] = acc;
    }
    __syncthreads();
#pragma unroll
    for (int i = 0; i < 32; ++i) {
        int idx = t + i * 256;
        int nl = idx >> 5, cj = idx & 31;
        int sp = n0 + nl;
        lepe_cn[((long)(b * CCH + (sp >> 4)) << 12) + (nl & 15) * 256 + c0 + cj] =
            __float2bfloat16(tile[nl][cj]);
    }
}

// ---------------------------------------------------------------------------
// Stage-2 MFMA attention + lepe add.  Writes final out[b][c][n].
__global__ __launch_bounds__(256)
void stage2_mfma(const __hip_bfloat16* __restrict__ qk_nc,
                 const __hip_bfloat16* __restrict__ st_md,
                 const __hip_bfloat16* __restrict__ sout_bf,
                 const __hip_bfloat16* __restrict__ lepe_cn,
                 float* __restrict__ out)
{
    __shared__ __hip_bfloat16 Es2[64 * 264];
    __shared__ __hip_bfloat16 sts[256 * 40];
    __shared__ __hip_bfloat16 sos[32 * 264];
    __shared__ float o_t[32 * 68];
    const int chunk = blockIdx.x, bh = blockIdx.y;
    const int b = bh >> 3, h = bh & 7;
    const int t = threadIdx.x, lane = t & 63, w = t >> 6;
    const int l15 = lane & 15, quad = lane >> 4;
    const int n0 = chunk * 256;

    {
        const int4* src = (const int4*)(st_md + ((long)(b * 256 + t)) * 256 + h * 32);
        int4* dst = (int4*)&sts[t * 40];
        dst[0] = src[0]; dst[1] = src[1]; dst[2] = src[2]; dst[3] = src[3];
    }
    {
        int row = t >> 3, seg = t & 7;
        const int4* src = (const int4*)(sout_bf + (long)bh * 8192 + row * 256 + seg * 32);
        int4* dst = (int4*)&sos[row * 264 + seg * 32];
        dst[0] = src[0]; dst[1] = src[1]; dst[2] = src[2]; dst[3] = src[3];
    }
    __syncthreads();
    bf16x8 stfrag[4];
#pragma unroll
    for (int mt = 0; mt < 4; ++mt)
        stfrag[mt] = *(const bf16x8*)&sts[(64 * w + mt * 16 + l15) * 40 + quad * 8];
    bf16x8 onesf;
    { short o = (l15 == 0) ? (short)0x3F80 : (short)0;
      onesf = bf16x8{o, o, o, o, o, o, o, o}; }

    for (int sub = 0; sub < 4; ++sub) {
        const int nbase = n0 + sub * 64;
#pragma unroll
        for (int nt = 0; nt < 4; ++nt) {
            bf16x8 qf = *(const bf16x8*)(qk_nc + ((long)b * 4096 + nbase + nt * 16 + l15) * 512 + h * 32 + quad * 8);
#pragma unroll
            for (int mt = 0; mt < 4; ++mt) {
                f32x4 s = __builtin_amdgcn_mfma_f32_16x16x32_bf16(qf, stfrag[mt], f32x4{0.f,0.f,0.f,0.f}, 0, 0, 0);
#pragma unroll
                for (int r = 0; r < 4; ++r)
                    Es2[(nt * 16 + quad * 4 + r) * 264 + 64 * w + mt * 16 + l15] =
                        __float2bfloat16(__expf(s[r] * SCALE));
            }
        }
        __syncthreads();
        f32x4 o0 = {0.f,0.f,0.f,0.f}, o1 = o0, o2 = o0;
#pragma unroll
        for (int ks = 0; ks < 8; ++ks) {
            bf16x8 af = *(const bf16x8*)&Es2[(16 * w + l15) * 264 + ks * 32 + quad * 8];
            bf16x8 b0 = *(const bf16x8*)&sos[(l15) * 264 + ks * 32 + quad * 8];
            bf16x8 b1 = *(const bf16x8*)&sos[(16 + l15) * 264 + ks * 32 + quad * 8];
            o0 = __builtin_amdgcn_mfma_f32_16x16x32_bf16(af, b0, o0, 0, 0, 0);
            o1 = __builtin_amdgcn_mfma_f32_16x16x32_bf16(af, b1, o1, 0, 0, 0);
            o2 = __builtin_amdgcn_mfma_f32_16x16x32_bf16(af, onesf, o2, 0, 0, 0);
        }
        __syncthreads();
#pragma unroll
        for (int r = 0; r < 4; ++r) {
            float den = __shfl(o2[r], lane & 48);
            float inv = 1.f / den;
            o_t[(l15) * 68 + 16 * w + quad * 4 + r]      = o0[r] * inv;
            o_t[(16 + l15) * 68 + 16 * w + quad * 4 + r] = o1[r] * inv;
        }
        __syncthreads();
        {   // add lepe + coalesced store of 32 rows x 64 cols
            int row = t >> 3, coff = (t & 7) * 8;
            long gb = ((long)(b * 256 + h * 32 + row)) * 4096 + nbase + coff;
            int4 lp4 = *(const int4*)(lepe_cn + gb);
            const __hip_bfloat16* lp = (const __hip_bfloat16*)&lp4;
            const float* sp = &o_t[row * 68 + coff];
            float4 r0, r1;
            r0.x = sp[0] + (float)lp[0]; r0.y = sp[1] + (float)lp[1];
            r0.z = sp[2] + (float)lp[2]; r0.w = sp[3] + (float)lp[3];
            r1.x = sp[4] + (float)lp[4]; r1.y = sp[5] + (float)lp[5];
            r1.z = sp[6] + (float)lp[6]; r1.w = sp[7] + (float)lp[7];
            *(float4*)(out + gb)     = r0;
            *(float4*)(out + gb + 4) = r1;
        }
        __syncthreads();
    }
}

// ---------------------------------------------------------------------------
extern "C" void kernel_launch(void* const* d_in, const int* in_sizes, int n_in,
                              void* d_out, int out_size, void* d_ws, size_t ws_size,
                              hipStream_t stream)
{
    const float* x    = (const float*)d_in[0];
    const float* aff  = (const float*)d_in[1];
    const float* nw   = (const float*)d_in[2];
    const float* nb   = (const float*)d_in[3];
    const float* Wq   = (const float*)d_in[4];
    const float* Wk   = (const float*)d_in[5];
    const float* Wv   = (const float*)d_in[6];
    const float* Wsp  = (const float*)d_in[7];
    const float* lw   = (const float*)d_in[8];
    const float* lb   = (const float*)d_in[9];
    float* out = (float*)d_out;

    float* ws = (float*)d_ws;
    const long P = PLANE;
    __hip_bfloat16* qk_nc  = (__hip_bfloat16*)(ws);           // [b][n][512] bf16
    __hip_bfloat16* v_cn   = (__hip_bfloat16*)(ws + 4 * P);   // [b][c][n] bf16
    __hip_bfloat16* xn_cn  = (__hip_bfloat16*)(ws + 6 * P);
    __hip_bfloat16* xn_nc  = (__hip_bfloat16*)(ws + 8 * P);
    __hip_bfloat16* lepe_cn= (__hip_bfloat16*)(ws + 10 * P);  // [b][c][n] bf16
    float* stoken_part = ws + 12 * P;                          // 32 x 65536 f32
    float* opart       = ws + 14 * P;                          // 16*32*256*33 f32
    float* tail        = ws + 14 * P + 4325376;
    __hip_bfloat16* wbf       = (__hip_bfloat16*)tail;         // [Wq;Wk;Wv;Wsp]
    __hip_bfloat16* stoken_bf = (__hip_bfloat16*)(tail + 131072);
    __hip_bfloat16* st_md     = (__hip_bfloat16*)(tail + 196608);
    __hip_bfloat16* sout_bf   = (__hip_bfloat16*)(tail + 327680);
    float* rs = tail + 458752;

    // 1. fused LayerNorm -> xn_cn + xn_nc
    ln_fused_kernel<<<256, 256, 0, stream>>>(x, nw, nb, xn_cn, xn_nc);
    // 2. weight casts + affinity row sums (one dispatch)
    prep_kernel<<<2048, 256, 0, stream>>>(aff, Wq, Wk, Wv, Wsp, wbf, rs);
    // 3. stoken partials (split-K=8, disjoint, deterministic)
    mfma_gemm_nt<0, false, true><<<dim3(4, 4, 32), 256, 0, stream>>>(
        aff, xn_cn, stoken_part, 256, 4096, 512, 3, P, P, 65536L, nullptr, 0);
    reduce8_cast_kernel<<<1024, 256, 0, stream>>>(stoken_part, stoken_bf);
    // 4. st_md[b][m][o] = stoken[m][.]·Wsp[o][.] / (rs[m]+eps)
    mfma_gemm_nt<1, true, false><<<dim3(4, 4, 4), 256, 0, stream>>>(
        stoken_bf, wbf + 3 * 65536, st_md, 256, 256, 256, 0, 65536L, 0L, 65536L, rs, 256L);
    // 5. fused q+k: qk_nc[b][n][o] = xn_nc[n][.]·[Wq;Wk][o][.]   (N=512)
    mfma_gemm_nt<1, false, false><<<dim3(8, 64, 4), 256, 0, stream>>>(
        xn_nc, wbf, qk_nc, 512, 256, 256, 0, P, 0L, 2 * P, nullptr, 0);
    // 6. v_cn[b][o][n] = Wv[o][.]·xn_nc[n][.]
    mfma_gemm_nt<1, false, false><<<dim3(64, 4, 4), 256, 0, stream>>>(
        wbf + 2 * 65536, xn_nc, v_cn, 4096, 256, 256, 0, 0L, P, P, nullptr, 0);
    // 7. lepe conv + scramble-transpose -> lepe_cn (final layout, bf16)
    lepe_conv_t_kernel<<<dim3(16, 8, BATCH), 256, 0, stream>>>(v_cn, lw, lb, lepe_cn);
    // 8. stage-1 MFMA attention partials
    stage1_mfma<<<dim3(16, 32), 256, 0, stream>>>(qk_nc, v_cn, st_md, opart);
    // 9. merge -> sout_bf
    merge1_kernel<<<1024, 256, 0, stream>>>(opart, sout_bf);
    // 10. stage-2 MFMA attention + lepe add -> d_out
    stage2_mfma<<<dim3(16, 32), 256, 0, stream>>>(qk_nc, st_md, sout_bf, lepe_cn, out);
}

// Round 7
// 240.558 us; speedup vs baseline: 3.7784x; 1.1591x over previous
//
#include <hip/hip_runtime.h>
#include <hip/hip_bf16.h>

#define BATCH 4
#define CCH   256
#define HWHW  4096
#define NSP   256
#define NHEAD 8
#define SCALE 0.17677669529663689f
#define PLANE 1048576L

typedef short bf16x8 __attribute__((ext_vector_type(8)));
typedef float f32x4  __attribute__((ext_vector_type(4)));

// ---------------------------------------------------------------------------
// Fused LayerNorm -> xn_cn [b][c][n] + xn_nc [b][n][c] (bf16).
// Blocks 0..255: LN (64 pixels/block).  Blocks 256..259: weight casts.
__global__ __launch_bounds__(256)
void ln_fused_kernel(const float* __restrict__ x, const float* __restrict__ w,
                     const float* __restrict__ bb,
                     const float* __restrict__ Wq, const float* __restrict__ Wk,
                     const float* __restrict__ Wv, const float* __restrict__ Wsp,
                     __hip_bfloat16* __restrict__ xn_cn,
                     __hip_bfloat16* __restrict__ xn_nc,
                     __hip_bfloat16* __restrict__ wbf)
{
    __shared__ __hip_bfloat16 xs[256][64];   // [c][p] bf16
    __shared__ float ps[4][64], pss[4][64], mus[64], rstds[64];
    __shared__ float wls[256], bls[256];
    int blk = blockIdx.x;
    int t = threadIdx.x;
    if (blk >= 256) {                        // weight casts
        int sel = blk - 256;
        const float* src = (sel == 0) ? Wq : (sel == 1) ? Wk : (sel == 2) ? Wv : Wsp;
        __hip_bfloat16* dst = wbf + sel * 65536;
        for (int i = t * 4; i < 65536; i += 1024) {
            float4 f = *(const float4*)(src + i);
            __hip_bfloat16 p[4];
            p[0] = __float2bfloat16(f.x); p[1] = __float2bfloat16(f.y);
            p[2] = __float2bfloat16(f.z); p[3] = __float2bfloat16(f.w);
            *(int2*)(dst + i) = *(int2*)p;
        }
        return;
    }
    int b = blk >> 6;
    int n0 = (blk & 63) * 64;
    int p = t & 63, cq = t >> 6;
    wls[t] = w[t]; bls[t] = bb[t];
    long base = (long)b * CCH * HWHW + n0 + p;
    float s = 0.f, ss = 0.f;
#pragma unroll 8
    for (int i = 0; i < 64; ++i) {
        int c = cq * 64 + i;
        float v = x[base + (long)c * HWHW];
        xs[c][p] = __float2bfloat16(v);
        s += v; ss += v * v;
    }
    ps[cq][p] = s; pss[cq][p] = ss;
    __syncthreads();
    if (cq == 0) {
        float S  = ps[0][p] + ps[1][p] + ps[2][p] + ps[3][p];
        float SS = pss[0][p] + pss[1][p] + pss[2][p] + pss[3][p];
        float mu = S * (1.f / 256.f);
        float var = SS * (1.f / 256.f) - mu * mu;
        mus[p] = mu; rstds[p] = rsqrtf(var + 1e-6f);
    }
    __syncthreads();
    float mu = mus[p], rstd = rstds[p];
#pragma unroll
    for (int c8 = 0; c8 < 8; ++c8) {
        short pack[8];
#pragma unroll
        for (int j = 0; j < 8; ++j) {
            int c = cq * 64 + c8 * 8 + j;
            float v = ((float)xs[c][p] - mu) * rstd * wls[c] + bls[c];
            __hip_bfloat16 bv = __float2bfloat16(v);
            xn_cn[(long)(b * CCH + c) * HWHW + n0 + p] = bv;
            pack[j] = *(short*)&bv;
        }
        *(int4*)(xn_nc + ((long)b * HWHW + n0 + p) * CCH + cq * 64 + c8 * 8) = *(int4*)pack;
    }
}

// ---------------------------------------------------------------------------
// Deterministic split-K(8) reduction -> stoken_bf; blocks 0..3 also reduce
// the rowsum partials -> rs[b*256+m].
__global__ __launch_bounds__(256)
void reduce8_cast_kernel(const float* __restrict__ part, const float* __restrict__ rsPart,
                         __hip_bfloat16* __restrict__ out, float* __restrict__ rs)
{
    int i = blockIdx.x * 256 + threadIdx.x;   // 262144
    if (blockIdx.x < 4) {                     // i < 1024: rowsum reduce
        int b = i >> 8, m = i & 255;
        float s = 0.f;
#pragma unroll
        for (int ch = 0; ch < 8; ++ch) s += rsPart[((b * 8 + ch) << 8) + m];
        rs[i] = s;
    }
    int b = i >> 16, idx = i & 65535;
    long base = (long)b * 8 * 65536 + idx;
    float s = 0.f;
#pragma unroll
    for (int ch = 0; ch < 8; ++ch) s += part[base + (long)ch * 65536];
    out[i] = __float2bfloat16(s);
}

// ---------------------------------------------------------------------------
// bf16 MFMA NT GEMM: C[m][n] = sum_k A[m][k]*B[n][k]
// OUTK: 0=f32, 1=bf16.  ROWSCALE: /(rowScale[m]+1e-16).  A32: fp32 A inline-cast.
// ROWSUM: also emit rsPart[z*256+m] = sum_k A[m][k] (ones-column MFMA trick).
template <int OUTK, bool ROWSCALE, bool A32, bool ROWSUM>
__global__ __launch_bounds__(256)
void mfma_gemm_nt(const void* __restrict__ Aptr, const __hip_bfloat16* __restrict__ B,
                  void* __restrict__ Cptr, int N, int K, int kChunk, int kShift,
                  long aStrideZ, long bStrideZ, long cStrideZ,
                  const float* __restrict__ rowScale, long sStrideZ,
                  float* __restrict__ rsPart)
{
    __shared__ __hip_bfloat16 Asm[4 * 64 * 8];
    __shared__ __hip_bfloat16 Bsm[4 * 64 * 8];
    int z = blockIdx.z;
    int b = z >> kShift;
    int ch = z & ((1 << kShift) - 1);
    int t = threadIdx.x;
    int lane = t & 63, w = t >> 6;
    int l15 = lane & 15, quad = lane >> 4;
    int Mt = blockIdx.y * 64, Nt = blockIdx.x * 64;

    const float* aSrcF = A32 ? ((const float*)Aptr + b * aStrideZ + (long)ch * kChunk
                                + (long)(Mt + w * 16 + l15) * K + quad * 8) : nullptr;
    const __hip_bfloat16* aSrcB = A32 ? nullptr :
        ((const __hip_bfloat16*)Aptr + b * aStrideZ + (long)ch * kChunk
         + (long)(Mt + w * 16 + l15) * K + quad * 8);
    const __hip_bfloat16* bSrc = B + b * bStrideZ + (long)ch * kChunk
        + (long)(Nt + w * 16 + l15) * K + quad * 8;
    __hip_bfloat16* aDst = &Asm[t * 8];
    __hip_bfloat16* bDst = &Bsm[t * 8];

    f32x4 acc00 = {0.f,0.f,0.f,0.f}, acc01 = acc00, acc10 = acc00, acc11 = acc00;
    f32x4 rs0 = acc00, rs1 = acc00;
    bf16x8 onesf;
    { short o = (l15 == 0) ? (short)0x3F80 : (short)0;
      onesf = bf16x8{o, o, o, o, o, o, o, o}; }
    int wm = (w & 1) * 2, wn = (w >> 1) * 2;

    for (int k0 = 0; k0 < kChunk; k0 += 32) {
        if (A32) {
            float4 f0 = ((const float4*)aSrcF)[0];
            float4 f1 = ((const float4*)aSrcF)[1];
            __hip_bfloat16 tmp[8];
            tmp[0]=__float2bfloat16(f0.x); tmp[1]=__float2bfloat16(f0.y);
            tmp[2]=__float2bfloat16(f0.z); tmp[3]=__float2bfloat16(f0.w);
            tmp[4]=__float2bfloat16(f1.x); tmp[5]=__float2bfloat16(f1.y);
            tmp[6]=__float2bfloat16(f1.z); tmp[7]=__float2bfloat16(f1.w);
            *(int4*)aDst = *(const int4*)tmp;
            aSrcF += 32;
        } else {
            *(int4*)aDst = *(const int4*)aSrcB;
            aSrcB += 32;
        }
        *(int4*)bDst = *(const int4*)bSrc;
        bSrc += 32;
        __syncthreads();
        bf16x8 a0 = ((const bf16x8*)Asm)[wm * 64 + lane];
        bf16x8 a1 = ((const bf16x8*)Asm)[(wm + 1) * 64 + lane];
        bf16x8 b0 = ((const bf16x8*)Bsm)[wn * 64 + lane];
        bf16x8 b1 = ((const bf16x8*)Bsm)[(wn + 1) * 64 + lane];
        acc00 = __builtin_amdgcn_mfma_f32_16x16x32_bf16(a0, b0, acc00, 0, 0, 0);
        acc01 = __builtin_amdgcn_mfma_f32_16x16x32_bf16(a0, b1, acc01, 0, 0, 0);
        acc10 = __builtin_amdgcn_mfma_f32_16x16x32_bf16(a1, b0, acc10, 0, 0, 0);
        acc11 = __builtin_amdgcn_mfma_f32_16x16x32_bf16(a1, b1, acc11, 0, 0, 0);
        if (ROWSUM) {
            rs0 = __builtin_amdgcn_mfma_f32_16x16x32_bf16(a0, onesf, rs0, 0, 0, 0);
            rs1 = __builtin_amdgcn_mfma_f32_16x16x32_bf16(a1, onesf, rs1, 0, 0, 0);
        }
        __syncthreads();
    }
    if (ROWSUM && blockIdx.x == 0 && (w >> 1) == 0 && l15 == 0) {
#pragma unroll
        for (int r = 0; r < 4; ++r) {
            rsPart[(long)z * 256 + Mt + wm * 16 + quad * 4 + r]       = rs0[r];
            rsPart[(long)z * 256 + Mt + (wm + 1) * 16 + quad * 4 + r] = rs1[r];
        }
    }
    f32x4 accs[2][2] = {{acc00, acc01}, {acc10, acc11}};
#pragma unroll
    for (int i = 0; i < 2; ++i)
#pragma unroll
        for (int j = 0; j < 2; ++j)
#pragma unroll
            for (int r = 0; r < 4; ++r) {
                int m = Mt + (wm + i) * 16 + quad * 4 + r;
                int n = Nt + (wn + j) * 16 + l15;
                float val = accs[i][j][r];
                if (ROWSCALE) val /= (rowScale[(long)b * sStrideZ + m] + 1e-16f);
                long off = (long)z * cStrideZ + (long)m * N + n;
                if (OUTK == 0) ((float*)Cptr)[off] = val;
                else ((__hip_bfloat16*)Cptr)[off] = __float2bfloat16(val);
            }
}

// ---------------------------------------------------------------------------
// Stage-1 MFMA attention partials.  k lives in qk_nc at column offset 256.
__global__ __launch_bounds__(256)
void stage1_mfma(const __hip_bfloat16* __restrict__ qk_nc,
                 const __hip_bfloat16* __restrict__ v_cn,
                 const __hip_bfloat16* __restrict__ st_md,
                 float* __restrict__ opart)
{
    __shared__ __hip_bfloat16 Es[256 * 72];
    __shared__ __hip_bfloat16 sts[256 * 40];
    const int chunk = blockIdx.x, bh = blockIdx.y;
    const int b = bh >> 3, h = bh & 7;
    const int t = threadIdx.x, lane = t & 63, w = t >> 6;
    const int l15 = lane & 15, quad = lane >> 4;
    const int n0 = chunk * 256;

    {
        const int4* src = (const int4*)(st_md + ((long)(b * 256 + t)) * 256 + h * 32);
        int4* dst = (int4*)&sts[t * 40];
        dst[0] = src[0]; dst[1] = src[1]; dst[2] = src[2]; dst[3] = src[3];
    }
    __syncthreads();
    bf16x8 afrag[16];
#pragma unroll
    for (int mt = 0; mt < 16; ++mt)
        afrag[mt] = *(const bf16x8*)&sts[(mt * 16 + l15) * 40 + quad * 8];
    bf16x8 onesf;
    { short o = (l15 == 0) ? (short)0x3F80 : (short)0;
      onesf = bf16x8{o, o, o, o, o, o, o, o}; }

    f32x4 occ[4][3];
#pragma unroll
    for (int i = 0; i < 4; ++i)
#pragma unroll
        for (int j = 0; j < 3; ++j) occ[i][j] = f32x4{0.f,0.f,0.f,0.f};

    for (int sub = 0; sub < 4; ++sub) {
        const int nbase = n0 + sub * 64;
        bf16x8 kf = *(const bf16x8*)(qk_nc + ((long)b * 4096 + nbase + 16 * w + l15) * 512 + 256 + h * 32 + quad * 8);
#pragma unroll
        for (int mt = 0; mt < 16; ++mt) {
            f32x4 s = __builtin_amdgcn_mfma_f32_16x16x32_bf16(afrag[mt], kf, f32x4{0.f,0.f,0.f,0.f}, 0, 0, 0);
#pragma unroll
            for (int r = 0; r < 4; ++r)
                Es[(mt * 16 + quad * 4 + r) * 72 + 16 * w + l15] =
                    __float2bfloat16(__expf(s[r] * SCALE));
        }
        __syncthreads();
#pragma unroll
        for (int ks = 0; ks < 2; ++ks) {
            bf16x8 bf0 = *(const bf16x8*)(v_cn + ((long)(b * 256 + h * 32 + l15)) * 4096 + nbase + ks * 32 + quad * 8);
            bf16x8 bf1 = *(const bf16x8*)(v_cn + ((long)(b * 256 + h * 32 + 16 + l15)) * 4096 + nbase + ks * 32 + quad * 8);
#pragma unroll
            for (int mi = 0; mi < 4; ++mi) {
                bf16x8 af = *(const bf16x8*)&Es[(64 * w + mi * 16 + l15) * 72 + ks * 32 + quad * 8];
                occ[mi][0] = __builtin_amdgcn_mfma_f32_16x16x32_bf16(af, bf0, occ[mi][0], 0, 0, 0);
                occ[mi][1] = __builtin_amdgcn_mfma_f32_16x16x32_bf16(af, bf1, occ[mi][1], 0, 0, 0);
                occ[mi][2] = __builtin_amdgcn_mfma_f32_16x16x32_bf16(af, onesf, occ[mi][2], 0, 0, 0);
            }
        }
        __syncthreads();
    }
    const long ob = ((long)chunk * 32 + bh) * 256 * 33;
#pragma unroll
    for (int mi = 0; mi < 4; ++mi)
#pragma unroll
        for (int jt = 0; jt < 3; ++jt) {
            if (jt == 2 && l15 != 0) continue;
            int col = jt * 16 + l15;
#pragma unroll
            for (int r = 0; r < 4; ++r) {
                int m = 64 * w + mi * 16 + quad * 4 + r;
                opart[ob + (long)m * 33 + col] = occ[mi][jt][r];
            }
        }
}

// Merge stage-1 partials -> sout_bf[bh][d][m]
__global__ __launch_bounds__(256)
void merge1_kernel(const float* __restrict__ opart, __hip_bfloat16* __restrict__ sout)
{
    int t = blockIdx.x * 256 + threadIdx.x;   // 262144
    int m = t & 255;
    int d = (t >> 8) & 31;
    int bh = t >> 13;
    float num = 0.f, den = 0.f;
    for (int ch = 0; ch < 16; ++ch) {
        long base = (((long)ch * 32 + bh) * 256 + m) * 33;
        num += opart[base + d];
        den += opart[base + 32];
    }
    sout[(long)bh * 8192 + d * 256 + m] = __float2bfloat16(num / den);
}

// ---------------------------------------------------------------------------
// Depthwise 3x3 conv + scramble-transpose -> lepe_cn (final [b][c][n], bf16).
// Block: 32 channels x 256 spatial (4 image rows).  LDS-staged halo window,
// lanes = columns (wave-uniform channel => conflict-free LDS), horizontal
// taps via shfl.
__global__ __launch_bounds__(256)
void lepe_conv_t_kernel(const __hip_bfloat16* __restrict__ v_cn,
                        const float* __restrict__ lw, const float* __restrict__ lb,
                        __hip_bfloat16* __restrict__ lepe_cn)
{
    __shared__ __hip_bfloat16 in_t[32 * 384];    // [ch][6 rows x 64]
    __shared__ __hip_bfloat16 tile_bf[256 * 33]; // [nl][ch]
    __shared__ float wls[288], bls[32];
    const int bx = blockIdx.x;           // 16 spatial tiles
    const int c0 = blockIdx.y * 32;      // 8 channel tiles
    const int b  = blockIdx.z;
    const int t = threadIdx.x;
    const int n0 = bx * 256, r0 = bx * 4;

    for (int i = t; i < 288; i += 256) wls[i] = lw[c0 * 9 + i];   // FIX: t<256 only
    if (t < 32)  bls[t] = lb[c0 + t];
    // stage halo window: 1536 x (8 bf16) vectors, contiguous per channel
#pragma unroll
    for (int i = 0; i < 6; ++i) {
        int vi = t + i * 256;
        int ch = vi / 48;
        int off = (vi % 48) * 8;
        int g = (r0 - 1) * 64 + off;
        int4 val = {0, 0, 0, 0};
        if ((unsigned)g < 4096u)
            val = *(const int4*)(v_cn + (((long)(b * CCH + c0 + ch)) << 12) + g);
        *(int4*)&in_t[ch * 384 + off] = val;
    }
    __syncthreads();

    const int lane = t & 63, w = t >> 6;
#pragma unroll
    for (int i = 0; i < 8; ++i) {
        int ch = w * 8 + i;
        float cr[6], lf[6], rf[6];
#pragma unroll
        for (int rr = 0; rr < 6; ++rr) {
            cr[rr] = (float)in_t[ch * 384 + rr * 64 + lane];
            float lv = __shfl_up(cr[rr], 1);
            float rv = __shfl_down(cr[rr], 1);
            lf[rr] = (lane == 0) ? 0.f : lv;
            rf[rr] = (lane == 63) ? 0.f : rv;
        }
        float w0 = wls[ch*9+0], w1 = wls[ch*9+1], w2 = wls[ch*9+2];
        float w3 = wls[ch*9+3], w4 = wls[ch*9+4], w5 = wls[ch*9+5];
        float w6 = wls[ch*9+6], w7 = wls[ch*9+7], w8 = wls[ch*9+8];
        float bias = bls[ch];
#pragma unroll
        for (int r = 0; r < 4; ++r) {
            float acc = bias
                + lf[r]   * w0 + cr[r]   * w1 + rf[r]   * w2
                + lf[r+1] * w3 + cr[r+1] * w4 + rf[r+1] * w5
                + lf[r+2] * w6 + cr[r+2] * w7 + rf[r+2] * w8;
            tile_bf[(r * 64 + lane) * 33 + ch] = __float2bfloat16(acc);
        }
    }
    __syncthreads();
    // scramble write: conv[b][c0+cj][n0+nl] -> lepe_cn[b][sp>>4][(sp&15)*256+c]
#pragma unroll
    for (int i = 0; i < 32; ++i) {
        int idx = t + i * 256;
        int nl = idx >> 5, cj = idx & 31;
        int sp = n0 + nl;
        lepe_cn[((long)(b * CCH + (sp >> 4)) << 12) + (nl & 15) * 256 + c0 + cj] =
            tile_bf[nl * 33 + cj];
    }
}

// ---------------------------------------------------------------------------
// Stage-2 MFMA attention + lepe add.  Writes final out[b][c][n].
__global__ __launch_bounds__(256)
void stage2_mfma(const __hip_bfloat16* __restrict__ qk_nc,
                 const __hip_bfloat16* __restrict__ st_md,
                 const __hip_bfloat16* __restrict__ sout_bf,
                 const __hip_bfloat16* __restrict__ lepe_cn,
                 float* __restrict__ out)
{
    __shared__ __hip_bfloat16 Es2[64 * 264];
    __shared__ __hip_bfloat16 sts[256 * 40];
    __shared__ __hip_bfloat16 sos[32 * 264];
    __shared__ float o_t[32 * 68];
    const int chunk = blockIdx.x, bh = blockIdx.y;
    const int b = bh >> 3, h = bh & 7;
    const int t = threadIdx.x, lane = t & 63, w = t >> 6;
    const int l15 = lane & 15, quad = lane >> 4;
    const int n0 = chunk * 256;

    {
        const int4* src = (const int4*)(st_md + ((long)(b * 256 + t)) * 256 + h * 32);
        int4* dst = (int4*)&sts[t * 40];
        dst[0] = src[0]; dst[1] = src[1]; dst[2] = src[2]; dst[3] = src[3];
    }
    {
        int row = t >> 3, seg = t & 7;
        const int4* src = (const int4*)(sout_bf + (long)bh * 8192 + row * 256 + seg * 32);
        int4* dst = (int4*)&sos[row * 264 + seg * 32];
        dst[0] = src[0]; dst[1] = src[1]; dst[2] = src[2]; dst[3] = src[3];
    }
    __syncthreads();
    bf16x8 stfrag[4];
#pragma unroll
    for (int mt = 0; mt < 4; ++mt)
        stfrag[mt] = *(const bf16x8*)&sts[(64 * w + mt * 16 + l15) * 40 + quad * 8];
    bf16x8 onesf;
    { short o = (l15 == 0) ? (short)0x3F80 : (short)0;
      onesf = bf16x8{o, o, o, o, o, o, o, o}; }

    for (int sub = 0; sub < 4; ++sub) {
        const int nbase = n0 + sub * 64;
#pragma unroll
        for (int nt = 0; nt < 4; ++nt) {
            bf16x8 qf = *(const bf16x8*)(qk_nc + ((long)b * 4096 + nbase + nt * 16 + l15) * 512 + h * 32 + quad * 8);
#pragma unroll
            for (int mt = 0; mt < 4; ++mt) {
                f32x4 s = __builtin_amdgcn_mfma_f32_16x16x32_bf16(qf, stfrag[mt], f32x4{0.f,0.f,0.f,0.f}, 0, 0, 0);
#pragma unroll
                for (int r = 0; r < 4; ++r)
                    Es2[(nt * 16 + quad * 4 + r) * 264 + 64 * w + mt * 16 + l15] =
                        __float2bfloat16(__expf(s[r] * SCALE));
            }
        }
        __syncthreads();
        f32x4 o0 = {0.f,0.f,0.f,0.f}, o1 = o0, o2 = o0;
#pragma unroll
        for (int ks = 0; ks < 8; ++ks) {
            bf16x8 af = *(const bf16x8*)&Es2[(16 * w + l15) * 264 + ks * 32 + quad * 8];
            bf16x8 b0 = *(const bf16x8*)&sos[(l15) * 264 + ks * 32 + quad * 8];
            bf16x8 b1 = *(const bf16x8*)&sos[(16 + l15) * 264 + ks * 32 + quad * 8];
            o0 = __builtin_amdgcn_mfma_f32_16x16x32_bf16(af, b0, o0, 0, 0, 0);
            o1 = __builtin_amdgcn_mfma_f32_16x16x32_bf16(af, b1, o1, 0, 0, 0);
            o2 = __builtin_amdgcn_mfma_f32_16x16x32_bf16(af, onesf, o2, 0, 0, 0);
        }
        __syncthreads();
#pragma unroll
        for (int r = 0; r < 4; ++r) {
            float den = __shfl(o2[r], lane & 48);
            float inv = 1.f / den;
            o_t[(l15) * 68 + 16 * w + quad * 4 + r]      = o0[r] * inv;
            o_t[(16 + l15) * 68 + 16 * w + quad * 4 + r] = o1[r] * inv;
        }
        __syncthreads();
        {
            int row = t >> 3, coff = (t & 7) * 8;
            long gb = ((long)(b * 256 + h * 32 + row)) * 4096 + nbase + coff;
            int4 lp4 = *(const int4*)(lepe_cn + gb);
            const __hip_bfloat16* lp = (const __hip_bfloat16*)&lp4;
            const float* sp = &o_t[row * 68 + coff];
            float4 r0, r1;
            r0.x = sp[0] + (float)lp[0]; r0.y = sp[1] + (float)lp[1];
            r0.z = sp[2] + (float)lp[2]; r0.w = sp[3] + (float)lp[3];
            r1.x = sp[4] + (float)lp[4]; r1.y = sp[5] + (float)lp[5];
            r1.z = sp[6] + (float)lp[6]; r1.w = sp[7] + (float)lp[7];
            *(float4*)(out + gb)     = r0;
            *(float4*)(out + gb + 4) = r1;
        }
        __syncthreads();
    }
}

// ---------------------------------------------------------------------------
extern "C" void kernel_launch(void* const* d_in, const int* in_sizes, int n_in,
                              void* d_out, int out_size, void* d_ws, size_t ws_size,
                              hipStream_t stream)
{
    const float* x    = (const float*)d_in[0];
    const float* aff  = (const float*)d_in[1];
    const float* nw   = (const float*)d_in[2];
    const float* nb   = (const float*)d_in[3];
    const float* Wq   = (const float*)d_in[4];
    const float* Wk   = (const float*)d_in[5];
    const float* Wv   = (const float*)d_in[6];
    const float* Wsp  = (const float*)d_in[7];
    const float* lw   = (const float*)d_in[8];
    const float* lb   = (const float*)d_in[9];
    float* out = (float*)d_out;

    float* ws = (float*)d_ws;
    const long P = PLANE;
    __hip_bfloat16* qk_nc  = (__hip_bfloat16*)(ws);           // [b][n][512] bf16
    __hip_bfloat16* v_cn   = (__hip_bfloat16*)(ws + 4 * P);   // [b][c][n] bf16
    __hip_bfloat16* xn_cn  = (__hip_bfloat16*)(ws + 6 * P);
    __hip_bfloat16* xn_nc  = (__hip_bfloat16*)(ws + 8 * P);
    __hip_bfloat16* lepe_cn= (__hip_bfloat16*)(ws + 10 * P);  // [b][c][n] bf16
    float* stoken_part = ws + 12 * P;                          // 32 x 65536 f32
    float* opart       = ws + 14 * P;                          // 16*32*256*33 f32
    float* tail        = ws + 14 * P + 4325376;
    // tail layout (floats) — all regions DISJOINT (fixed round-4 overlap):
    __hip_bfloat16* wbf       = (__hip_bfloat16*)tail;              // [0,131072)
    __hip_bfloat16* stoken_bf = (__hip_bfloat16*)(tail + 131072);   // [131072,262144)
    __hip_bfloat16* st_md     = (__hip_bfloat16*)(tail + 262144);   // [262144,393216)
    __hip_bfloat16* sout_bf   = (__hip_bfloat16*)(tail + 393216);   // [393216,524288)
    float* rs      = tail + 524288;                                  // 1024
    float* rs_part = tail + 525312;                                  // 8192

    // 1. fused LayerNorm (blocks 0..255) + weight casts (blocks 256..259)
    ln_fused_kernel<<<260, 256, 0, stream>>>(x, nw, nb, Wq, Wk, Wv, Wsp,
                                             xn_cn, xn_nc, wbf);
    // 2. stoken partials (split-K=8) + rowsum partials (ones-column trick)
    mfma_gemm_nt<0, false, true, true><<<dim3(4, 4, 32), 256, 0, stream>>>(
        aff, xn_cn, stoken_part, 256, 4096, 512, 3, P, P, 65536L, nullptr, 0, rs_part);
    // 3. reduce stoken + rowsums
    reduce8_cast_kernel<<<1024, 256, 0, stream>>>(stoken_part, rs_part, stoken_bf, rs);
    // 4. st_md[b][m][o] = stoken[m][.]·Wsp[o][.] / (rs[m]+eps)
    mfma_gemm_nt<1, true, false, false><<<dim3(4, 4, 4), 256, 0, stream>>>(
        stoken_bf, wbf + 3 * 65536, st_md, 256, 256, 256, 0, 65536L, 0L, 65536L, rs, 256L, nullptr);
    // 5. fused q+k: qk_nc[b][n][o] = xn_nc[n][.]·[Wq;Wk][o][.]
    mfma_gemm_nt<1, false, false, false><<<dim3(8, 64, 4), 256, 0, stream>>>(
        xn_nc, wbf, qk_nc, 512, 256, 256, 0, P, 0L, 2 * P, nullptr, 0, nullptr);
    // 6. v_cn[b][o][n] = Wv[o][.]·xn_nc[n][.]
    mfma_gemm_nt<1, false, false, false><<<dim3(64, 4, 4), 256, 0, stream>>>(
        wbf + 2 * 65536, xn_nc, v_cn, 4096, 256, 256, 0, 0L, P, P, nullptr, 0, nullptr);
    // 7. lepe conv + scramble-transpose -> lepe_cn
    lepe_conv_t_kernel<<<dim3(16, 8, BATCH), 256, 0, stream>>>(v_cn, lw, lb, lepe_cn);
    // 8. stage-1 MFMA attention partials
    stage1_mfma<<<dim3(16, 32), 256, 0, stream>>>(qk_nc, v_cn, st_md, opart);
    // 9. merge -> sout_bf
    merge1_kernel<<<1024, 256, 0, stream>>>(opart, sout_bf);
    // 10. stage-2 MFMA attention + lepe add -> d_out
    stage2_mfma<<<dim3(16, 32), 256, 0, stream>>>(qk_nc, st_md, sout_bf, lepe_cn, out);
}

// Round 8
// 212.243 us; speedup vs baseline: 4.2825x; 1.1334x over previous
//
#include <hip/hip_runtime.h>
#include <hip/hip_bf16.h>

#define BATCH 4
#define CCH   256
#define HWHW  4096
#define NSP   256
#define NHEAD 8
#define SCALE 0.17677669529663689f
#define PLANE 1048576L

typedef short bf16x8 __attribute__((ext_vector_type(8)));
typedef float f32x4  __attribute__((ext_vector_type(4)));

// ---------------------------------------------------------------------------
// Fused LayerNorm -> xn_cn [b][c][n] + xn_nc [b][n][c] (bf16).
// Blocks 0..255: LN.  256..259: weight casts.  260..323: aff fp32->bf16.
__global__ __launch_bounds__(256)
void ln_fused_kernel(const float* __restrict__ x, const float* __restrict__ w,
                     const float* __restrict__ bb,
                     const float* __restrict__ Wq, const float* __restrict__ Wk,
                     const float* __restrict__ Wv, const float* __restrict__ Wsp,
                     const float* __restrict__ aff,
                     __hip_bfloat16* __restrict__ xn_cn,
                     __hip_bfloat16* __restrict__ xn_nc,
                     __hip_bfloat16* __restrict__ wbf,
                     __hip_bfloat16* __restrict__ aff_bf)
{
    __shared__ __hip_bfloat16 xs[256][72];   // pitch 72 (bank-rotating for b128 reads)
    __shared__ float ps[4][64], pss[4][64], mus[64], rstds[64];
    __shared__ float wls[256], bls[256];
    int blk = blockIdx.x;
    int t = threadIdx.x;
    if (blk >= 256) {
        int sel = blk - 256;
        if (sel < 4) {                       // weight casts
            const float* src = (sel == 0) ? Wq : (sel == 1) ? Wk : (sel == 2) ? Wv : Wsp;
            __hip_bfloat16* dst = wbf + sel * 65536;
            for (int i = t * 4; i < 65536; i += 1024) {
                float4 f = *(const float4*)(src + i);
                __hip_bfloat16 p[4];
                p[0] = __float2bfloat16(f.x); p[1] = __float2bfloat16(f.y);
                p[2] = __float2bfloat16(f.z); p[3] = __float2bfloat16(f.w);
                *(int2*)(dst + i) = *(int2*)p;
            }
        } else {                             // aff cast (64 segs of 65536)
            long base = (long)(sel - 4) * 65536;
            for (int i = t * 4; i < 65536; i += 1024) {
                float4 f = *(const float4*)(aff + base + i);
                __hip_bfloat16 p[4];
                p[0] = __float2bfloat16(f.x); p[1] = __float2bfloat16(f.y);
                p[2] = __float2bfloat16(f.z); p[3] = __float2bfloat16(f.w);
                *(int2*)(aff_bf + base + i) = *(int2*)p;
            }
        }
        return;
    }
    int b = blk >> 6;
    int n0 = (blk & 63) * 64;
    int p = t & 63, cq = t >> 6;
    wls[t] = w[t]; bls[t] = bb[t];
    long base = (long)b * CCH * HWHW + n0 + p;
    float s = 0.f, ss = 0.f;
#pragma unroll 8
    for (int i = 0; i < 64; ++i) {
        int c = cq * 64 + i;
        float v = x[base + (long)c * HWHW];
        xs[c][p] = __float2bfloat16(v);
        s += v; ss += v * v;
    }
    ps[cq][p] = s; pss[cq][p] = ss;
    __syncthreads();
    if (cq == 0) {
        float S  = ps[0][p] + ps[1][p] + ps[2][p] + ps[3][p];
        float SS = pss[0][p] + pss[1][p] + pss[2][p] + pss[3][p];
        float mu = S * (1.f / 256.f);
        float var = SS * (1.f / 256.f) - mu * mu;
        mus[p] = mu; rstds[p] = rsqrtf(var + 1e-6f);
    }
    __syncthreads();
    float mu = mus[p], rstd = rstds[p];
#pragma unroll
    for (int c8 = 0; c8 < 8; ++c8) {
        short pack[8];
#pragma unroll
        for (int j = 0; j < 8; ++j) {
            int c = cq * 64 + c8 * 8 + j;
            float v = ((float)xs[c][p] - mu) * rstd * wls[c] + bls[c];
            __hip_bfloat16 bv = __float2bfloat16(v);
            xs[c][p] = bv;                   // write back normalized
            pack[j] = *(short*)&bv;
        }
        *(int4*)(xn_nc + ((long)b * HWHW + n0 + p) * CCH + cq * 64 + c8 * 8) = *(int4*)pack;
    }
    __syncthreads();
    // vectorized xn_cn store: 8 passes, b128 per (c, 8-n segment)
#pragma unroll
    for (int i = 0; i < 8; ++i) {
        int idx = t + i * 256;
        int c = idx >> 3, seg = idx & 7;
        *(int4*)(xn_cn + (long)(b * CCH + c) * HWHW + n0 + seg * 8) =
            *(const int4*)&xs[c][seg * 8];
    }
}

// ---------------------------------------------------------------------------
// Deterministic split-K(8) reduction -> stoken_bf; blocks 0..3 also reduce
// the rowsum partials -> rs[b*256+m].
__global__ __launch_bounds__(256)
void reduce8_cast_kernel(const float* __restrict__ part, const float* __restrict__ rsPart,
                         __hip_bfloat16* __restrict__ out, float* __restrict__ rs)
{
    int i = blockIdx.x * 256 + threadIdx.x;   // 262144
    if (blockIdx.x < 4) {                     // i < 1024: rowsum reduce
        int b = i >> 8, m = i & 255;
        float s = 0.f;
#pragma unroll
        for (int ch = 0; ch < 8; ++ch) s += rsPart[((b * 8 + ch) << 8) + m];
        rs[i] = s;
    }
    int b = i >> 16, idx = i & 65535;
    long base = (long)b * 8 * 65536 + idx;
    float s = 0.f;
#pragma unroll
    for (int ch = 0; ch < 8; ++ch) s += part[base + (long)ch * 65536];
    out[i] = __float2bfloat16(s);
}

// ---------------------------------------------------------------------------
// bf16 MFMA NT GEMM, software-pipelined (prefetch next K-tile into regs).
// C[m][n] = sum_k A[m][k]*B[n][k].  OUTK: 0=f32, 1=bf16.
// ROWSCALE: /(rowScale[m]+1e-16).  ROWSUM: emit rsPart[z*256+m].
template <int OUTK, bool ROWSCALE, bool ROWSUM>
__global__ __launch_bounds__(256)
void mfma_gemm_nt(const __hip_bfloat16* __restrict__ A, const __hip_bfloat16* __restrict__ B,
                  void* __restrict__ Cptr, int N, int K, int kChunk, int kShift,
                  long aStrideZ, long bStrideZ, long cStrideZ,
                  const float* __restrict__ rowScale, long sStrideZ,
                  float* __restrict__ rsPart)
{
    __shared__ __hip_bfloat16 Asm[4 * 64 * 8];
    __shared__ __hip_bfloat16 Bsm[4 * 64 * 8];
    int z = blockIdx.z;
    int b = z >> kShift;
    int ch = z & ((1 << kShift) - 1);
    int t = threadIdx.x;
    int lane = t & 63, w = t >> 6;
    int l15 = lane & 15, quad = lane >> 4;
    int Mt = blockIdx.y * 64, Nt = blockIdx.x * 64;

    const __hip_bfloat16* aSrc = A + b * aStrideZ + (long)ch * kChunk
        + (long)(Mt + w * 16 + l15) * K + quad * 8;
    const __hip_bfloat16* bSrc = B + b * bStrideZ + (long)ch * kChunk
        + (long)(Nt + w * 16 + l15) * K + quad * 8;
    __hip_bfloat16* aDst = &Asm[t * 8];
    __hip_bfloat16* bDst = &Bsm[t * 8];

    f32x4 acc00 = {0.f,0.f,0.f,0.f}, acc01 = acc00, acc10 = acc00, acc11 = acc00;
    f32x4 rs0 = acc00, rs1 = acc00;
    bf16x8 onesf;
    { short o = (l15 == 0) ? (short)0x3F80 : (short)0;
      onesf = bf16x8{o, o, o, o, o, o, o, o}; }
    int wm = (w & 1) * 2, wn = (w >> 1) * 2;

    int4 aReg = *(const int4*)aSrc;
    int4 bReg = *(const int4*)bSrc;
    for (int k0 = 0; k0 < kChunk; k0 += 32) {
        *(int4*)aDst = aReg;
        *(int4*)bDst = bReg;
        __syncthreads();
        if (k0 + 32 < kChunk) {               // prefetch next tile
            aSrc += 32; bSrc += 32;
            aReg = *(const int4*)aSrc;
            bReg = *(const int4*)bSrc;
        }
        bf16x8 a0 = ((const bf16x8*)Asm)[wm * 64 + lane];
        bf16x8 a1 = ((const bf16x8*)Asm)[(wm + 1) * 64 + lane];
        bf16x8 b0 = ((const bf16x8*)Bsm)[wn * 64 + lane];
        bf16x8 b1 = ((const bf16x8*)Bsm)[(wn + 1) * 64 + lane];
        acc00 = __builtin_amdgcn_mfma_f32_16x16x32_bf16(a0, b0, acc00, 0, 0, 0);
        acc01 = __builtin_amdgcn_mfma_f32_16x16x32_bf16(a0, b1, acc01, 0, 0, 0);
        acc10 = __builtin_amdgcn_mfma_f32_16x16x32_bf16(a1, b0, acc10, 0, 0, 0);
        acc11 = __builtin_amdgcn_mfma_f32_16x16x32_bf16(a1, b1, acc11, 0, 0, 0);
        if (ROWSUM) {
            rs0 = __builtin_amdgcn_mfma_f32_16x16x32_bf16(a0, onesf, rs0, 0, 0, 0);
            rs1 = __builtin_amdgcn_mfma_f32_16x16x32_bf16(a1, onesf, rs1, 0, 0, 0);
        }
        __syncthreads();
    }
    if (ROWSUM && blockIdx.x == 0 && (w >> 1) == 0 && l15 == 0) {
#pragma unroll
        for (int r = 0; r < 4; ++r) {
            rsPart[(long)z * 256 + Mt + wm * 16 + quad * 4 + r]       = rs0[r];
            rsPart[(long)z * 256 + Mt + (wm + 1) * 16 + quad * 4 + r] = rs1[r];
        }
    }
    f32x4 accs[2][2] = {{acc00, acc01}, {acc10, acc11}};
#pragma unroll
    for (int i = 0; i < 2; ++i)
#pragma unroll
        for (int j = 0; j < 2; ++j)
#pragma unroll
            for (int r = 0; r < 4; ++r) {
                int m = Mt + (wm + i) * 16 + quad * 4 + r;
                int n = Nt + (wn + j) * 16 + l15;
                float val = accs[i][j][r];
                if (ROWSCALE) val /= (rowScale[(long)b * sStrideZ + m] + 1e-16f);
                long off = (long)z * cStrideZ + (long)m * N + n;
                if (OUTK == 0) ((float*)Cptr)[off] = val;
                else ((__hip_bfloat16*)Cptr)[off] = __float2bfloat16(val);
            }
}

// ---------------------------------------------------------------------------
// Stage-1 MFMA attention partials.  k lives in qk_nc at column offset 256.
// opart layout: [chunk][bh][col(33)][m(256)] bf16 — coalesced write (LDS
// transpose through the dead Es buffer) and coalesced merge read.
__global__ __launch_bounds__(256)
void stage1_mfma(const __hip_bfloat16* __restrict__ qk_nc,
                 const __hip_bfloat16* __restrict__ v_cn,
                 const __hip_bfloat16* __restrict__ st_md,
                 __hip_bfloat16* __restrict__ opart)
{
    __shared__ __hip_bfloat16 Es[256 * 72];
    __shared__ __hip_bfloat16 sts[256 * 40];
    const int chunk = blockIdx.x, bh = blockIdx.y;
    const int b = bh >> 3, h = bh & 7;
    const int t = threadIdx.x, lane = t & 63, w = t >> 6;
    const int l15 = lane & 15, quad = lane >> 4;
    const int n0 = chunk * 256;

    {
        const int4* src = (const int4*)(st_md + ((long)(b * 256 + t)) * 256 + h * 32);
        int4* dst = (int4*)&sts[t * 40];
        dst[0] = src[0]; dst[1] = src[1]; dst[2] = src[2]; dst[3] = src[3];
    }
    __syncthreads();
    bf16x8 afrag[16];
#pragma unroll
    for (int mt = 0; mt < 16; ++mt)
        afrag[mt] = *(const bf16x8*)&sts[(mt * 16 + l15) * 40 + quad * 8];
    bf16x8 onesf;
    { short o = (l15 == 0) ? (short)0x3F80 : (short)0;
      onesf = bf16x8{o, o, o, o, o, o, o, o}; }

    f32x4 occ[4][3];
#pragma unroll
    for (int i = 0; i < 4; ++i)
#pragma unroll
        for (int j = 0; j < 3; ++j) occ[i][j] = f32x4{0.f,0.f,0.f,0.f};

    for (int sub = 0; sub < 4; ++sub) {
        const int nbase = n0 + sub * 64;
        bf16x8 kf = *(const bf16x8*)(qk_nc + ((long)b * 4096 + nbase + 16 * w + l15) * 512 + 256 + h * 32 + quad * 8);
#pragma unroll
        for (int mt = 0; mt < 16; ++mt) {
            f32x4 s = __builtin_amdgcn_mfma_f32_16x16x32_bf16(afrag[mt], kf, f32x4{0.f,0.f,0.f,0.f}, 0, 0, 0);
#pragma unroll
            for (int r = 0; r < 4; ++r)
                Es[(mt * 16 + quad * 4 + r) * 72 + 16 * w + l15] =
                    __float2bfloat16(__expf(s[r] * SCALE));
        }
        __syncthreads();
#pragma unroll
        for (int ks = 0; ks < 2; ++ks) {
            bf16x8 bf0 = *(const bf16x8*)(v_cn + ((long)(b * 256 + h * 32 + l15)) * 4096 + nbase + ks * 32 + quad * 8);
            bf16x8 bf1 = *(const bf16x8*)(v_cn + ((long)(b * 256 + h * 32 + 16 + l15)) * 4096 + nbase + ks * 32 + quad * 8);
#pragma unroll
            for (int mi = 0; mi < 4; ++mi) {
                bf16x8 af = *(const bf16x8*)&Es[(64 * w + mi * 16 + l15) * 72 + ks * 32 + quad * 8];
                occ[mi][0] = __builtin_amdgcn_mfma_f32_16x16x32_bf16(af, bf0, occ[mi][0], 0, 0, 0);
                occ[mi][1] = __builtin_amdgcn_mfma_f32_16x16x32_bf16(af, bf1, occ[mi][1], 0, 0, 0);
                occ[mi][2] = __builtin_amdgcn_mfma_f32_16x16x32_bf16(af, onesf, occ[mi][2], 0, 0, 0);
            }
        }
        __syncthreads();
    }
    // transpose partials through LDS (Es dead): tb[col][m], pitch 264 bf16
    __hip_bfloat16* tb = Es;
#pragma unroll
    for (int mi = 0; mi < 4; ++mi)
#pragma unroll
        for (int jt = 0; jt < 3; ++jt) {
            if (jt == 2 && l15 != 0) continue;
            int col = jt * 16 + l15;
#pragma unroll
            for (int r = 0; r < 4; ++r) {
                int m = 64 * w + mi * 16 + quad * 4 + r;
                tb[col * 264 + m] = __float2bfloat16(occ[mi][jt][r]);
            }
        }
    __syncthreads();
    // coalesced global write: 33 rows x 256 bf16 = 4224 ints
    int* og = (int*)(opart) + (long)(chunk * 32 + bh) * 4224;
    const int* tbi = (const int*)tb;
#pragma unroll
    for (int i = 0; i < 17; ++i) {
        int idx = t + i * 256;
        if (idx < 4224) {
            int row = idx >> 7, off = idx & 127;
            og[idx] = tbi[row * 132 + off];
        }
    }
}

// Merge stage-1 partials -> sout_bf[bh][d][m]  (coalesced bf16 reads)
__global__ __launch_bounds__(256)
void merge1_kernel(const __hip_bfloat16* __restrict__ opart, __hip_bfloat16* __restrict__ sout)
{
    int t = blockIdx.x * 256 + threadIdx.x;   // 262144
    int m = t & 255;
    int d = (t >> 8) & 31;
    int bh = t >> 13;
    float num = 0.f, den = 0.f;
    for (int ch = 0; ch < 16; ++ch) {
        long base = (long)((ch * 32 + bh) * 33) * 256 + m;
        num += (float)opart[base + (long)d * 256];
        den += (float)opart[base + 32 * 256];
    }
    sout[(long)bh * 8192 + d * 256 + m] = __float2bfloat16(num / den);
}

// ---------------------------------------------------------------------------
// Depthwise 3x3 conv + scramble-transpose -> lepe_cn (final [b][c][n], bf16).
__global__ __launch_bounds__(256)
void lepe_conv_t_kernel(const __hip_bfloat16* __restrict__ v_cn,
                        const float* __restrict__ lw, const float* __restrict__ lb,
                        __hip_bfloat16* __restrict__ lepe_cn)
{
    __shared__ __hip_bfloat16 in_t[32 * 384];
    __shared__ __hip_bfloat16 tile_bf[256 * 33];
    __shared__ float wls[288], bls[32];
    const int bx = blockIdx.x;
    const int c0 = blockIdx.y * 32;
    const int b  = blockIdx.z;
    const int t = threadIdx.x;
    const int n0 = bx * 256, r0 = bx * 4;

    for (int i = t; i < 288; i += 256) wls[i] = lw[c0 * 9 + i];
    if (t < 32)  bls[t] = lb[c0 + t];
#pragma unroll
    for (int i = 0; i < 6; ++i) {
        int vi = t + i * 256;
        int ch = vi / 48;
        int off = (vi % 48) * 8;
        int g = (r0 - 1) * 64 + off;
        int4 val = {0, 0, 0, 0};
        if ((unsigned)g < 4096u)
            val = *(const int4*)(v_cn + (((long)(b * CCH + c0 + ch)) << 12) + g);
        *(int4*)&in_t[ch * 384 + off] = val;
    }
    __syncthreads();

    const int lane = t & 63, w = t >> 6;
#pragma unroll
    for (int i = 0; i < 8; ++i) {
        int ch = w * 8 + i;
        float cr[6], lf[6], rf[6];
#pragma unroll
        for (int rr = 0; rr < 6; ++rr) {
            cr[rr] = (float)in_t[ch * 384 + rr * 64 + lane];
            float lv = __shfl_up(cr[rr], 1);
            float rv = __shfl_down(cr[rr], 1);
            lf[rr] = (lane == 0) ? 0.f : lv;
            rf[rr] = (lane == 63) ? 0.f : rv;
        }
        float w0 = wls[ch*9+0], w1 = wls[ch*9+1], w2 = wls[ch*9+2];
        float w3 = wls[ch*9+3], w4 = wls[ch*9+4], w5 = wls[ch*9+5];
        float w6 = wls[ch*9+6], w7 = wls[ch*9+7], w8 = wls[ch*9+8];
        float bias = bls[ch];
#pragma unroll
        for (int r = 0; r < 4; ++r) {
            float acc = bias
                + lf[r]   * w0 + cr[r]   * w1 + rf[r]   * w2
                + lf[r+1] * w3 + cr[r+1] * w4 + rf[r+1] * w5
                + lf[r+2] * w6 + cr[r+2] * w7 + rf[r+2] * w8;
            tile_bf[(r * 64 + lane) * 33 + ch] = __float2bfloat16(acc);
        }
    }
    __syncthreads();
#pragma unroll
    for (int i = 0; i < 32; ++i) {
        int idx = t + i * 256;
        int nl = idx >> 5, cj = idx & 31;
        int sp = n0 + nl;
        lepe_cn[((long)(b * CCH + (sp >> 4)) << 12) + (nl & 15) * 256 + c0 + cj] =
            tile_bf[nl * 33 + cj];
    }
}

// ---------------------------------------------------------------------------
// Stage-2 MFMA attention + lepe add.  Writes final out[b][c][n].
__global__ __launch_bounds__(256)
void stage2_mfma(const __hip_bfloat16* __restrict__ qk_nc,
                 const __hip_bfloat16* __restrict__ st_md,
                 const __hip_bfloat16* __restrict__ sout_bf,
                 const __hip_bfloat16* __restrict__ lepe_cn,
                 float* __restrict__ out)
{
    __shared__ __hip_bfloat16 Es2[64 * 264];
    __shared__ __hip_bfloat16 sts[256 * 40];
    __shared__ __hip_bfloat16 sos[32 * 264];
    __shared__ float o_t[32 * 68];
    const int chunk = blockIdx.x, bh = blockIdx.y;
    const int b = bh >> 3, h = bh & 7;
    const int t = threadIdx.x, lane = t & 63, w = t >> 6;
    const int l15 = lane & 15, quad = lane >> 4;
    const int n0 = chunk * 256;

    {
        const int4* src = (const int4*)(st_md + ((long)(b * 256 + t)) * 256 + h * 32);
        int4* dst = (int4*)&sts[t * 40];
        dst[0] = src[0]; dst[1] = src[1]; dst[2] = src[2]; dst[3] = src[3];
    }
    {
        int row = t >> 3, seg = t & 7;
        const int4* src = (const int4*)(sout_bf + (long)bh * 8192 + row * 256 + seg * 32);
        int4* dst = (int4*)&sos[row * 264 + seg * 32];
        dst[0] = src[0]; dst[1] = src[1]; dst[2] = src[2]; dst[3] = src[3];
    }
    __syncthreads();
    bf16x8 stfrag[4];
#pragma unroll
    for (int mt = 0; mt < 4; ++mt)
        stfrag[mt] = *(const bf16x8*)&sts[(64 * w + mt * 16 + l15) * 40 + quad * 8];
    bf16x8 onesf;
    { short o = (l15 == 0) ? (short)0x3F80 : (short)0;
      onesf = bf16x8{o, o, o, o, o, o, o, o}; }

    for (int sub = 0; sub < 4; ++sub) {
        const int nbase = n0 + sub * 64;
#pragma unroll
        for (int nt = 0; nt < 4; ++nt) {
            bf16x8 qf = *(const bf16x8*)(qk_nc + ((long)b * 4096 + nbase + nt * 16 + l15) * 512 + h * 32 + quad * 8);
#pragma unroll
            for (int mt = 0; mt < 4; ++mt) {
                f32x4 s = __builtin_amdgcn_mfma_f32_16x16x32_bf16(qf, stfrag[mt], f32x4{0.f,0.f,0.f,0.f}, 0, 0, 0);
#pragma unroll
                for (int r = 0; r < 4; ++r)
                    Es2[(nt * 16 + quad * 4 + r) * 264 + 64 * w + mt * 16 + l15] =
                        __float2bfloat16(__expf(s[r] * SCALE));
            }
        }
        __syncthreads();
        f32x4 o0 = {0.f,0.f,0.f,0.f}, o1 = o0, o2 = o0;
#pragma unroll
        for (int ks = 0; ks < 8; ++ks) {
            bf16x8 af = *(const bf16x8*)&Es2[(16 * w + l15) * 264 + ks * 32 + quad * 8];
            bf16x8 b0 = *(const bf16x8*)&sos[(l15) * 264 + ks * 32 + quad * 8];
            bf16x8 b1 = *(const bf16x8*)&sos[(16 + l15) * 264 + ks * 32 + quad * 8];
            o0 = __builtin_amdgcn_mfma_f32_16x16x32_bf16(af, b0, o0, 0, 0, 0);
            o1 = __builtin_amdgcn_mfma_f32_16x16x32_bf16(af, b1, o1, 0, 0, 0);
            o2 = __builtin_amdgcn_mfma_f32_16x16x32_bf16(af, onesf, o2, 0, 0, 0);
        }
        __syncthreads();
#pragma unroll
        for (int r = 0; r < 4; ++r) {
            float den = __shfl(o2[r], lane & 48);
            float inv = 1.f / den;
            o_t[(l15) * 68 + 16 * w + quad * 4 + r]      = o0[r] * inv;
            o_t[(16 + l15) * 68 + 16 * w + quad * 4 + r] = o1[r] * inv;
        }
        __syncthreads();
        {
            int row = t >> 3, coff = (t & 7) * 8;
            long gb = ((long)(b * 256 + h * 32 + row)) * 4096 + nbase + coff;
            int4 lp4 = *(const int4*)(lepe_cn + gb);
            const __hip_bfloat16* lp = (const __hip_bfloat16*)&lp4;
            const float* sp = &o_t[row * 68 + coff];
            float4 r0, r1;
            r0.x = sp[0] + (float)lp[0]; r0.y = sp[1] + (float)lp[1];
            r0.z = sp[2] + (float)lp[2]; r0.w = sp[3] + (float)lp[3];
            r1.x = sp[4] + (float)lp[4]; r1.y = sp[5] + (float)lp[5];
            r1.z = sp[6] + (float)lp[6]; r1.w = sp[7] + (float)lp[7];
            *(float4*)(out + gb)     = r0;
            *(float4*)(out + gb + 4) = r1;
        }
        __syncthreads();
    }
}

// ---------------------------------------------------------------------------
extern "C" void kernel_launch(void* const* d_in, const int* in_sizes, int n_in,
                              void* d_out, int out_size, void* d_ws, size_t ws_size,
                              hipStream_t stream)
{
    const float* x    = (const float*)d_in[0];
    const float* aff  = (const float*)d_in[1];
    const float* nw   = (const float*)d_in[2];
    const float* nb   = (const float*)d_in[3];
    const float* Wq   = (const float*)d_in[4];
    const float* Wk   = (const float*)d_in[5];
    const float* Wv   = (const float*)d_in[6];
    const float* Wsp  = (const float*)d_in[7];
    const float* lw   = (const float*)d_in[8];
    const float* lb   = (const float*)d_in[9];
    float* out = (float*)d_out;

    float* ws = (float*)d_ws;
    const long P = PLANE;
    __hip_bfloat16* qk_nc  = (__hip_bfloat16*)(ws);           // [b][n][512] bf16 (16.8MB)
    __hip_bfloat16* v_cn   = (__hip_bfloat16*)(ws + 4 * P);   // [b][c][n]
    __hip_bfloat16* xn_cn  = (__hip_bfloat16*)(ws + 6 * P);
    __hip_bfloat16* xn_nc  = (__hip_bfloat16*)(ws + 8 * P);
    __hip_bfloat16* lepe_cn= (__hip_bfloat16*)(ws + 10 * P);
    __hip_bfloat16* aff_bf = (__hip_bfloat16*)(ws + 12 * P);  // 4.19M bf16
    float* stoken_part = ws + 14 * P;                          // 32 x 65536 f32
    __hip_bfloat16* opart = (__hip_bfloat16*)(ws + 16 * P);    // 16*32*33*256 bf16
    float* tail        = ws + 16 * P + 2162688;
    __hip_bfloat16* wbf       = (__hip_bfloat16*)tail;
    __hip_bfloat16* stoken_bf = (__hip_bfloat16*)(tail + 131072);
    __hip_bfloat16* st_md     = (__hip_bfloat16*)(tail + 262144);
    __hip_bfloat16* sout_bf   = (__hip_bfloat16*)(tail + 393216);
    float* rs      = tail + 524288;
    float* rs_part = tail + 525312;

    // 1. fused LayerNorm + weight casts + aff cast
    ln_fused_kernel<<<324, 256, 0, stream>>>(x, nw, nb, Wq, Wk, Wv, Wsp, aff,
                                             xn_cn, xn_nc, wbf, aff_bf);
    // 2. stoken partials (split-K=8, pipelined) + rowsum partials
    mfma_gemm_nt<0, false, true><<<dim3(4, 4, 32), 256, 0, stream>>>(
        aff_bf, xn_cn, stoken_part, 256, 4096, 512, 3, P, P, 65536L, nullptr, 0, rs_part);
    // 3. reduce stoken + rowsums
    reduce8_cast_kernel<<<1024, 256, 0, stream>>>(stoken_part, rs_part, stoken_bf, rs);
    // 4. st_md = stoken·Wsp / (rs+eps)
    mfma_gemm_nt<1, true, false><<<dim3(4, 4, 4), 256, 0, stream>>>(
        stoken_bf, wbf + 3 * 65536, st_md, 256, 256, 256, 0, 65536L, 0L, 65536L, rs, 256L, nullptr);
    // 5. fused q+k
    mfma_gemm_nt<1, false, false><<<dim3(8, 64, 4), 256, 0, stream>>>(
        xn_nc, wbf, qk_nc, 512, 256, 256, 0, P, 0L, 2 * P, nullptr, 0, nullptr);
    // 6. v_cn
    mfma_gemm_nt<1, false, false><<<dim3(64, 4, 4), 256, 0, stream>>>(
        wbf + 2 * 65536, xn_nc, v_cn, 4096, 256, 256, 0, 0L, P, P, nullptr, 0, nullptr);
    // 7. lepe conv + scramble-transpose
    lepe_conv_t_kernel<<<dim3(16, 8, BATCH), 256, 0, stream>>>(v_cn, lw, lb, lepe_cn);
    // 8. stage-1 attention partials (coalesced bf16 opart)
    stage1_mfma<<<dim3(16, 32), 256, 0, stream>>>(qk_nc, v_cn, st_md, opart);
    // 9. merge -> sout_bf
    merge1_kernel<<<1024, 256, 0, stream>>>(opart, sout_bf);
    // 10. stage-2 attention + lepe add -> d_out
    stage2_mfma<<<dim3(16, 32), 256, 0, stream>>>(qk_nc, st_md, sout_bf, lepe_cn, out);
}